// Round 6
// baseline (2501.217 us; speedup 1.0000x reference)
//
#include <hip/hip_runtime.h>
#include <math.h>

#define NTOK 73728

__device__ __forceinline__ float gelu_f(float x) {
    return 0.5f * x * (1.0f + erff(x * 0.70710678118654752440f));
}

// ================= prep: norms, fused dec weights, transposes =================
__global__ void __launch_bounds__(256) k_prep(
    const float* __restrict__ cb_s, const float* __restrict__ cb_x,
    double* __restrict__ cn_s, double* __restrict__ cn_x,
    float* __restrict__ cnf_s, float* __restrict__ cnf_x,
    const float* __restrict__ s_dw1, const float* __restrict__ s_db1,
    const float* __restrict__ s_dfcw, const float* __restrict__ s_dfcb,
    float* __restrict__ weffT_s, float* __restrict__ beff_s,
    const float* __restrict__ x_dw1, const float* __restrict__ x_db1,
    const float* __restrict__ x_dfcw, const float* __restrict__ x_dfcb,
    float* __restrict__ weffT_x, float* __restrict__ beff_x,
    const float* __restrict__ s_fcw, float* __restrict__ fcwT_s,
    const float* __restrict__ x_fcw, float* __restrict__ fcwT_x,
    const float* __restrict__ s_w2, float* __restrict__ sw2T,
    const float* __restrict__ x_w1, float* __restrict__ xw1T,
    const float* __restrict__ x_w2, float* __restrict__ xw2T,
    const float* __restrict__ x_dw2, float* __restrict__ xdw2T)
{
    int bid = blockIdx.x, tid = threadIdx.x;
    if (bid < 8) {                     // codebook norms (f64 + f32 copy)
        int i = bid * 256 + tid;
        const float* cb = (i < 1024) ? cb_s : cb_x;
        double* cn = (i < 1024) ? cn_s : cn_x;
        float* cnf = (i < 1024) ? cnf_s : cnf_x;
        int c = i & 1023;
        double s = 0.0;
        for (int k = 0; k < 64; ++k) { double v = (double)cb[c * 64 + k]; s += v * v; }
        cn[c] = s;
        cnf[c] = (float)s;
    } else if (bid < 40) {             // weffT_s
        int idx = (bid - 8) * 256 + tid;
        int o = idx >> 6, d = idx & 63;
        int c = o >> 3, l = o & 7;
        double acc = 0.0;
        for (int ci = 0; ci < 16; ++ci)
            for (int dd = 0; dd < 3; ++dd) {
                int ll = l + dd - 1;
                if (ll < 0 || ll > 7) continue;
                acc += (double)s_dw1[(c * 16 + ci) * 3 + dd] * (double)s_dfcw[(ci * 8 + ll) * 64 + d];
            }
        weffT_s[d * 132 + o] = (float)acc;
        if (o < 4) weffT_s[d * 132 + 128 + o] = 0.f;
        if (d == 0) {
            double bb = (double)s_db1[c];
            for (int ci = 0; ci < 16; ++ci)
                for (int dd = 0; dd < 3; ++dd) {
                    int ll = l + dd - 1;
                    if (ll < 0 || ll > 7) continue;
                    bb += (double)s_dw1[(c * 16 + ci) * 3 + dd] * (double)s_dfcb[ci * 8 + ll];
                }
            beff_s[o] = (float)bb;
        }
    } else if (bid < 76) {             // weffT_x
        int idx = (bid - 40) * 256 + tid;
        int o = idx >> 6, d = idx & 63;
        int c = o / 9, p = o - c * 9;
        int i = p / 3, j = p % 3;
        double acc = 0.0;
        for (int ci = 0; ci < 16; ++ci)
            for (int di = 0; di < 3; ++di) {
                int ii = i + di - 1; if (ii < 0 || ii > 2) continue;
                for (int dj = 0; dj < 3; ++dj) {
                    int jj = j + dj - 1; if (jj < 0 || jj > 2) continue;
                    acc += (double)x_dw1[((c * 16 + ci) * 3 + di) * 3 + dj]
                         * (double)x_dfcw[(ci * 9 + ii * 3 + jj) * 64 + d];
                }
            }
        weffT_x[d * 148 + o] = (float)acc;
        if (o < 4) weffT_x[d * 148 + 144 + o] = 0.f;
        if (d == 0) {
            double bb = (double)x_db1[c];
            for (int ci = 0; ci < 16; ++ci)
                for (int di = 0; di < 3; ++di) {
                    int ii = i + di - 1; if (ii < 0 || ii > 2) continue;
                    for (int dj = 0; dj < 3; ++dj) {
                        int jj = j + dj - 1; if (jj < 0 || jj > 2) continue;
                        bb += (double)x_dw1[((c * 16 + ci) * 3 + di) * 3 + dj]
                            * (double)x_dfcb[ci * 9 + ii * 3 + jj];
                    }
                }
            beff_x[o] = (float)bb;
        }
    } else if (bid < 108) {            // fcwT_s
        int i = (bid - 76) * 256 + tid;
        fcwT_s[i] = s_fcw[(i & 63) * 128 + (i >> 6)];
    } else if (bid < 144) {            // fcwT_x
        int i = (bid - 108) * 256 + tid;
        fcwT_x[i] = x_fcw[(i & 63) * 144 + (i >> 6)];
    } else {                           // small conv-weight transposes
        int i = (bid - 144) * 256 + tid;
        if (i < 768) {
            int c = i & 15, r = i >> 4;
            int ci = r / 3, dd = r % 3;
            sw2T[i] = s_w2[(c * 16 + ci) * 3 + dd];
        } else if (i < 1920) {
            int j = i - 768;
            int c = j & 15, r = j >> 4;
            int ci = r / 9, tap = r % 9;
            xw1T[j] = x_w1[(c * 8 + ci) * 9 + tap];
        } else if (i < 4224) {
            int j = i - 1920;
            int c = j & 15, r = j >> 4;
            int ci = r / 9, tap = r % 9;
            xw2T[j] = x_w2[(c * 16 + ci) * 9 + tap];
        } else {
            int j = i - 4224;
            int co = j & 7, r = j >> 3;
            int ci = r / 9, tap = r % 9;
            xdw2T[j] = x_dw2[(co * 16 + ci) * 9 + tap];
        }
    }
}

// ================= spectral encoder =================
__global__ void __launch_bounds__(256) k_spec_enc(
    const float* __restrict__ cubes,
    const float* __restrict__ w1, const float* __restrict__ b1,
    const float* __restrict__ sw2T, const float* __restrict__ b2,
    const float* __restrict__ fcwT, const float* __restrict__ fcb,
    float* __restrict__ z_out)
{
    __shared__ float S[16 * 8];
    __shared__ float A[16 * 136];
    __shared__ float Bb[16 * 136];
    int tid = threadIdx.x;
    int t = tid >> 4, c = tid & 15;
    if (tid < 128) {
        int tk = tid >> 3, f = tid & 7;
        const float* cu = cubes + ((size_t)blockIdx.x * 16 + tk) * 72 + f * 9;
        float s = 0.f;
        #pragma unroll
        for (int k = 0; k < 9; ++k) s += cu[k];
        S[tk * 8 + f] = s * (1.0f / 9.0f);
    }
    __syncthreads();
    {   // conv1 1->16
        float s0[8];
        *(float4*)&s0[0] = *(const float4*)&S[t * 8];
        *(float4*)&s0[4] = *(const float4*)&S[t * 8 + 4];
        float wa = w1[c * 3 + 0], wb = w1[c * 3 + 1], wc = w1[c * 3 + 2], bb = b1[c];
        #pragma unroll
        for (int l = 0; l < 8; ++l) {
            float v = fmaf(wb, s0[l], bb);
            if (l > 0) v = fmaf(wa, s0[l - 1], v);
            if (l < 7) v = fmaf(wc, s0[l + 1], v);
            A[t * 136 + c * 8 + l] = gelu_f(v);
        }
    }
    __syncthreads();
    {   // conv2 16->16
        float acc[8];
        #pragma unroll
        for (int l = 0; l < 8; ++l) acc[l] = b2[c];
        for (int ci = 0; ci < 16; ++ci) {
            float r[8];
            *(float4*)&r[0] = *(const float4*)&A[t * 136 + ci * 8];
            *(float4*)&r[4] = *(const float4*)&A[t * 136 + ci * 8 + 4];
            float wa = sw2T[(ci * 3 + 0) * 16 + c];
            float wb = sw2T[(ci * 3 + 1) * 16 + c];
            float wc = sw2T[(ci * 3 + 2) * 16 + c];
            #pragma unroll
            for (int l = 0; l < 8; ++l) {
                if (l > 0) acc[l] = fmaf(wa, r[l - 1], acc[l]);
                acc[l] = fmaf(wb, r[l], acc[l]);
                if (l < 7) acc[l] = fmaf(wc, r[l + 1], acc[l]);
            }
        }
        #pragma unroll
        for (int l = 0; l < 8; ++l) Bb[t * 136 + c * 8 + l] = gelu_f(acc[l]);
    }
    __syncthreads();
    {   // fc 128->64
        float4 zv = make_float4(fcb[c * 4 + 0], fcb[c * 4 + 1], fcb[c * 4 + 2], fcb[c * 4 + 3]);
        #pragma unroll 4
        for (int e = 0; e < 128; ++e) {
            float be = Bb[t * 136 + e];
            float4 wv = *(const float4*)(fcwT + (e << 6) + (c << 2));
            zv.x = fmaf(wv.x, be, zv.x);
            zv.y = fmaf(wv.y, be, zv.y);
            zv.z = fmaf(wv.z, be, zv.z);
            zv.w = fmaf(wv.w, be, zv.w);
        }
        *(float4*)(z_out + ((size_t)blockIdx.x * 16 + t) * 64 + c * 4) = zv;
    }
}

// ================= spatial encoder =================
__global__ void __launch_bounds__(256) k_spat_enc(
    const float* __restrict__ cubes,
    const float* __restrict__ xw1T, const float* __restrict__ b1,
    const float* __restrict__ xw2T, const float* __restrict__ b2,
    const float* __restrict__ fcwT, const float* __restrict__ fcb,
    float* __restrict__ z_out)
{
    __shared__ float A[16 * 200];
    __shared__ float Bb[16 * 200];
    int tid = threadIdx.x;
    int t = tid >> 4, c = tid & 15;
    for (int u = tid; u < 1152; u += 256) {
        int tk = u / 72, e = u - tk * 72;
        int ci = e / 9, p = e - ci * 9;
        A[tk * 200 + ci * 12 + p] = cubes[(size_t)blockIdx.x * 1152 + u];
    }
    __syncthreads();
    {   // conv1 8->16
        float acc[9];
        #pragma unroll
        for (int p = 0; p < 9; ++p) acc[p] = b1[c];
        for (int ci = 0; ci < 8; ++ci) {
            float r[12];
            *(float4*)&r[0] = *(const float4*)&A[t * 200 + ci * 12];
            *(float4*)&r[4] = *(const float4*)&A[t * 200 + ci * 12 + 4];
            *(float4*)&r[8] = *(const float4*)&A[t * 200 + ci * 12 + 8];
            float wv[9];
            #pragma unroll
            for (int q = 0; q < 9; ++q) wv[q] = xw1T[(ci * 9 + q) * 16 + c];
            #pragma unroll
            for (int p = 0; p < 9; ++p) {
                int i = p / 3, j = p % 3;
                #pragma unroll
                for (int di = 0; di < 3; ++di) {
                    int ii = i + di - 1; if (ii < 0 || ii > 2) continue;
                    #pragma unroll
                    for (int dj = 0; dj < 3; ++dj) {
                        int jj = j + dj - 1; if (jj < 0 || jj > 2) continue;
                        acc[p] = fmaf(wv[di * 3 + dj], r[ii * 3 + jj], acc[p]);
                    }
                }
            }
        }
        #pragma unroll
        for (int p = 0; p < 9; ++p) Bb[t * 200 + c * 12 + p] = gelu_f(acc[p]);
    }
    __syncthreads();
    {   // conv2 16->16
        float acc[9];
        #pragma unroll
        for (int p = 0; p < 9; ++p) acc[p] = b2[c];
        for (int ci = 0; ci < 16; ++ci) {
            float r[12];
            *(float4*)&r[0] = *(const float4*)&Bb[t * 200 + ci * 12];
            *(float4*)&r[4] = *(const float4*)&Bb[t * 200 + ci * 12 + 4];
            *(float4*)&r[8] = *(const float4*)&Bb[t * 200 + ci * 12 + 8];
            float wv[9];
            #pragma unroll
            for (int q = 0; q < 9; ++q) wv[q] = xw2T[(ci * 9 + q) * 16 + c];
            #pragma unroll
            for (int p = 0; p < 9; ++p) {
                int i = p / 3, j = p % 3;
                #pragma unroll
                for (int di = 0; di < 3; ++di) {
                    int ii = i + di - 1; if (ii < 0 || ii > 2) continue;
                    #pragma unroll
                    for (int dj = 0; dj < 3; ++dj) {
                        int jj = j + dj - 1; if (jj < 0 || jj > 2) continue;
                        acc[p] = fmaf(wv[di * 3 + dj], r[ii * 3 + jj], acc[p]);
                    }
                }
            }
        }
        __syncthreads();
        #pragma unroll
        for (int p = 0; p < 9; ++p) A[t * 200 + c * 12 + p] = gelu_f(acc[p]);
    }
    __syncthreads();
    {   // fc 144->64
        float4 zv = make_float4(fcb[c * 4 + 0], fcb[c * 4 + 1], fcb[c * 4 + 2], fcb[c * 4 + 3]);
        #pragma unroll 4
        for (int e = 0; e < 144; ++e) {
            int ci = e / 9, p = e - ci * 9;
            float be = A[t * 200 + ci * 12 + p];
            float4 wv = *(const float4*)(fcwT + (e << 6) + (c << 2));
            zv.x = fmaf(wv.x, be, zv.x);
            zv.y = fmaf(wv.y, be, zv.y);
            zv.z = fmaf(wv.z, be, zv.z);
            zv.w = fmaf(wv.w, be, zv.w);
        }
        *(float4*)(z_out + ((size_t)blockIdx.x * 16 + t) * 64 + c * 4) = zv;
    }
}

// ===== VQ: 64 tokens/block, 8 waves x 128-code chunks, f32 scan + f64 certify =====
__global__ void __launch_bounds__(512) k_vq(
    float* __restrict__ emb, const float* __restrict__ cb,
    const double* __restrict__ cn, const float* __restrict__ cnf,
    float* __restrict__ idx_out, int* __restrict__ hist,
    double* __restrict__ partial)
{
    __shared__ float pb1[8][64];
    __shared__ float pb2[8][64];
    __shared__ int   pi1[8][64];
    int tid = threadIdx.x;
    int w = tid >> 6, l = tid & 63;
    size_t n = (size_t)blockIdx.x * 64 + l;
    float z[64];
    {
        const float4* zp = (const float4*)(emb + n * 64);
        #pragma unroll
        for (int k = 0; k < 16; ++k) *(float4*)&z[k * 4] = zp[k];
    }
    // wave-uniform chunk base -> SGPR loads
    int base = __builtin_amdgcn_readfirstlane(w << 7);
    const float* crb = cb + ((size_t)base << 6);
    const float* cnfb = cnf + base;
    float b1 = 1e30f, b2 = 1e30f; int i1 = base;
    for (int cc = 0; cc < 128; ++cc) {
        const float* cr = crb + (cc << 6);
        float d0 = 0.f, d1 = 0.f, d2 = 0.f, d3 = 0.f;
        #pragma unroll
        for (int k = 0; k < 64; k += 4) {
            d0 = fmaf(z[k + 0], cr[k + 0], d0);
            d1 = fmaf(z[k + 1], cr[k + 1], d1);
            d2 = fmaf(z[k + 2], cr[k + 2], d2);
            d3 = fmaf(z[k + 3], cr[k + 3], d3);
        }
        float dot = (d0 + d1) + (d2 + d3);
        float dd = cnfb[cc] - 2.0f * dot;
        if (dd < b1) { b2 = b1; b1 = dd; i1 = base + cc; }   // strict <: first-index
        else if (dd < b2) b2 = dd;
    }
    pb1[w][l] = b1; pb2[w][l] = b2; pi1[w][l] = i1;
    __syncthreads();
    if (w == 0) {
        // top-2 merge over 8 ascending chunks
        b1 = pb1[0][l]; b2 = pb2[0][l]; i1 = pi1[0][l];
        #pragma unroll
        for (int q = 1; q < 8; ++q) {
            float a1 = pb1[q][l], a2 = pb2[q][l];
            if (a1 < b1) { b2 = fminf(b1, a2); b1 = a1; i1 = pi1[q][l]; }
            else { b2 = fminf(b2, a1); }
        }
        // certainty margin: |d32 - d64| < ~5e-6, margin 3e-4 -> provably exact winner
        unsigned long long mask = __ballot(b2 - b1 < 3e-4f);
        while (mask) {       // cooperative exact f64 rescan for rare near-tie tokens
            int tk = __ffsll((long long)mask) - 1; mask &= (mask - 1);
            float zz[64];
            #pragma unroll
            for (int k = 0; k < 64; ++k) zz[k] = __shfl(z[k], tk);
            double bd = 1e300; int bl = 0;
            for (int cc = 0; cc < 16; ++cc) {
                int c = l * 16 + cc;                 // per-lane ascending code ranges
                const float* cr = cb + ((size_t)c << 6);
                double dot = 0.0;
                #pragma unroll
                for (int k = 0; k < 64; ++k) dot = fma((double)zz[k], (double)cr[k], dot);
                double dd = cn[c] - 2.0 * dot;
                if (dd < bd) { bd = dd; bl = c; }
            }
            #pragma unroll
            for (int m = 1; m < 64; m <<= 1) {       // lexicographic (d, idx) min
                double ob = __shfl_xor(bd, m);
                int oi = __shfl_xor(bl, m);
                if (ob < bd || (ob == bd && oi < bl)) { bd = ob; bl = oi; }
            }
            if (l == tk) i1 = bl;
        }
        idx_out[n] = (float)i1;
        float qv[64];
        {
            const float4* cq = (const float4*)(cb + ((size_t)i1 << 6));
            #pragma unroll
            for (int k = 0; k < 16; ++k) *(float4*)&qv[k * 4] = cq[k];
        }
        float vs = 0.f;
        #pragma unroll
        for (int k = 0; k < 64; ++k) { float df = z[k] - qv[k]; vs = fmaf(df, df, vs); }
        float4* zo = (float4*)(emb + n * 64);
        #pragma unroll
        for (int k = 0; k < 16; ++k) zo[k] = *(float4*)&qv[k * 4];
        atomicAdd(&hist[i1], 1);
        double s = (double)vs;
        #pragma unroll
        for (int o = 32; o > 0; o >>= 1) s += __shfl_down(s, o);
        if (l == 0) partial[blockIdx.x] = s;
    }
}

// ================= spectral decoder + recon loss =================
__global__ void __launch_bounds__(256) k_spec_dec(
    const float* __restrict__ emb, const float* __restrict__ cubes,
    const float* __restrict__ weffT, const float* __restrict__ beff,
    const float* __restrict__ w2, const float* __restrict__ b2,
    double* __restrict__ partial)
{
    __shared__ float Z[16 * 72];
    __shared__ float Bb[16 * 136];
    __shared__ float S[16 * 8];
    __shared__ double wred[4];
    int tid = threadIdx.x;
    int t = tid >> 4, c = tid & 15;
    {
        int tk = tid >> 4, dq = tid & 15;
        *(float4*)&Z[tk * 72 + dq * 4] =
            *(const float4*)(emb + (size_t)blockIdx.x * 1024 + (size_t)tid * 4);
    }
    if (tid < 128) {
        int tk = tid >> 3, f = tid & 7;
        const float* cu = cubes + ((size_t)blockIdx.x * 16 + tk) * 72 + f * 9;
        float s = 0.f;
        #pragma unroll
        for (int k = 0; k < 9; ++k) s += cu[k];
        S[tk * 8 + f] = s * (1.0f / 9.0f);
    }
    __syncthreads();
    float zr[64];
    #pragma unroll
    for (int k = 0; k < 16; ++k) *(float4*)&zr[k * 4] = *(const float4*)&Z[t * 72 + k * 4];
    {
        float4 a0 = make_float4(0.f, 0.f, 0.f, 0.f);
        float4 a1 = make_float4(0.f, 0.f, 0.f, 0.f);
        #pragma unroll 8
        for (int k = 0; k < 64; ++k) {
            float zk = zr[k];
            float4 w0 = *(const float4*)(weffT + k * 132 + (c << 2));
            float4 w1v = *(const float4*)(weffT + k * 132 + 64 + (c << 2));
            a0.x = fmaf(w0.x, zk, a0.x); a0.y = fmaf(w0.y, zk, a0.y);
            a0.z = fmaf(w0.z, zk, a0.z); a0.w = fmaf(w0.w, zk, a0.w);
            a1.x = fmaf(w1v.x, zk, a1.x); a1.y = fmaf(w1v.y, zk, a1.y);
            a1.z = fmaf(w1v.z, zk, a1.z); a1.w = fmaf(w1v.w, zk, a1.w);
        }
        int o0 = c << 2, o1 = 64 + (c << 2);
        float4 g0 = make_float4(gelu_f(a0.x + beff[o0 + 0]), gelu_f(a0.y + beff[o0 + 1]),
                                gelu_f(a0.z + beff[o0 + 2]), gelu_f(a0.w + beff[o0 + 3]));
        float4 g1 = make_float4(gelu_f(a1.x + beff[o1 + 0]), gelu_f(a1.y + beff[o1 + 1]),
                                gelu_f(a1.z + beff[o1 + 2]), gelu_f(a1.w + beff[o1 + 3]));
        *(float4*)&Bb[t * 136 + o0] = g0;
        *(float4*)&Bb[t * 136 + o1] = g1;
    }
    __syncthreads();
    float acc2 = 0.f;
    {   // conv2 16->1 + loss
        int h = c >> 3, pos = c & 7;
        float a = (h == 0) ? b2[0] : 0.f;
        for (int ci = h * 8; ci < h * 8 + 8; ++ci) {
            const float* w = w2 + ci * 3;
            const float* hb = &Bb[t * 136 + ci * 8];
            if (pos > 0) a = fmaf(w[0], hb[pos - 1], a);
            a = fmaf(w[1], hb[pos], a);
            if (pos < 7) a = fmaf(w[2], hb[pos + 1], a);
        }
        a += __shfl_xor(a, 8);
        if (h == 0) { float df = a - S[t * 8 + pos]; acc2 = df * df; }
    }
    double s = (double)acc2;
    #pragma unroll
    for (int o = 32; o > 0; o >>= 1) s += __shfl_down(s, o);
    if ((tid & 63) == 0) wred[tid >> 6] = s;
    __syncthreads();
    if (tid == 0) partial[blockIdx.x] = wred[0] + wred[1] + wred[2] + wred[3];
}

// ================= spatial decoder + recon loss =================
__global__ void __launch_bounds__(256) k_spat_dec(
    const float* __restrict__ emb, const float* __restrict__ cubes,
    const float* __restrict__ weffT, const float* __restrict__ beff,
    const float* __restrict__ xdw2T, const float* __restrict__ b2,
    double* __restrict__ partial)
{
    __shared__ float Z[16 * 72];
    __shared__ float H[16 * 200];
    __shared__ float T[16 * 104];
    __shared__ double wred[4];
    int tid = threadIdx.x;
    int t = tid >> 4, c = tid & 15;
    {
        int tk = tid >> 4, dq = tid & 15;
        *(float4*)&Z[tk * 72 + dq * 4] =
            *(const float4*)(emb + (size_t)blockIdx.x * 1024 + (size_t)tid * 4);
    }
    for (int u = tid; u < 1152; u += 256) {
        int tk = u / 72, e = u - tk * 72;
        int ci = e / 9, p = e - ci * 9;
        T[tk * 104 + ci * 12 + p] = cubes[(size_t)blockIdx.x * 1152 + u];
    }
    __syncthreads();
    float zr[64];
    #pragma unroll
    for (int k = 0; k < 16; ++k) *(float4*)&zr[k * 4] = *(const float4*)&Z[t * 72 + k * 4];
    {
        float4 a0 = make_float4(0.f, 0.f, 0.f, 0.f);
        float4 a1 = make_float4(0.f, 0.f, 0.f, 0.f);
        float4 a2 = make_float4(0.f, 0.f, 0.f, 0.f);
        #pragma unroll 8
        for (int k = 0; k < 64; ++k) {
            float zk = zr[k];
            float4 w0 = *(const float4*)(weffT + k * 148 + (c << 2));
            float4 w1v = *(const float4*)(weffT + k * 148 + 64 + (c << 2));
            float4 w2v = *(const float4*)(weffT + k * 148 + 128 + (c << 2));
            a0.x = fmaf(w0.x, zk, a0.x); a0.y = fmaf(w0.y, zk, a0.y);
            a0.z = fmaf(w0.z, zk, a0.z); a0.w = fmaf(w0.w, zk, a0.w);
            a1.x = fmaf(w1v.x, zk, a1.x); a1.y = fmaf(w1v.y, zk, a1.y);
            a1.z = fmaf(w1v.z, zk, a1.z); a1.w = fmaf(w1v.w, zk, a1.w);
            a2.x = fmaf(w2v.x, zk, a2.x); a2.y = fmaf(w2v.y, zk, a2.y);
            a2.z = fmaf(w2v.z, zk, a2.z); a2.w = fmaf(w2v.w, zk, a2.w);
        }
        float av[12] = {a0.x, a0.y, a0.z, a0.w, a1.x, a1.y, a1.z, a1.w, a2.x, a2.y, a2.z, a2.w};
        #pragma unroll
        for (int q = 0; q < 12; ++q) {
            int o = (c << 2) + ((q >> 2) << 6) + (q & 3);
            int ch = o / 9, p = o - ch * 9;
            H[t * 200 + ch * 12 + p] = gelu_f(av[q] + beff[o]);
        }
    }
    __syncthreads();
    float acc2 = 0.f;
    {   // conv2 16->8 + loss
        int co = c >> 1, h = c & 1;
        float accp[9];
        #pragma unroll
        for (int p = 0; p < 9; ++p) accp[p] = (h == 0) ? b2[co] : 0.f;
        for (int ci = h * 8; ci < h * 8 + 8; ++ci) {
            float r[12];
            *(float4*)&r[0] = *(const float4*)&H[t * 200 + ci * 12];
            *(float4*)&r[4] = *(const float4*)&H[t * 200 + ci * 12 + 4];
            *(float4*)&r[8] = *(const float4*)&H[t * 200 + ci * 12 + 8];
            float wv[9];
            #pragma unroll
            for (int q = 0; q < 9; ++q) wv[q] = xdw2T[(ci * 9 + q) * 8 + co];
            #pragma unroll
            for (int p = 0; p < 9; ++p) {
                int i = p / 3, j = p % 3;
                #pragma unroll
                for (int di = 0; di < 3; ++di) {
                    int ii = i + di - 1; if (ii < 0 || ii > 2) continue;
                    #pragma unroll
                    for (int dj = 0; dj < 3; ++dj) {
                        int jj = j + dj - 1; if (jj < 0 || jj > 2) continue;
                        accp[p] = fmaf(wv[di * 3 + dj], r[ii * 3 + jj], accp[p]);
                    }
                }
            }
        }
        #pragma unroll
        for (int p = 0; p < 9; ++p) {
            float tot = accp[p] + __shfl_xor(accp[p], 1);
            if (h == 0) { float df = tot - T[t * 104 + co * 12 + p]; acc2 = fmaf(df, df, acc2); }
        }
    }
    double s = (double)acc2;
    #pragma unroll
    for (int o = 32; o > 0; o >>= 1) s += __shfl_down(s, o);
    if ((tid & 63) == 0) wred[tid >> 6] = s;
    __syncthreads();
    if (tid == 0) partial[blockIdx.x] = wred[0] + wred[1] + wred[2] + wred[3];
}

// ================= finalize scalars =================
__global__ void __launch_bounds__(256) k_final(
    const double* __restrict__ p_vq_s, const double* __restrict__ p_vq_x,
    const double* __restrict__ p_rec_s, const double* __restrict__ p_rec_x,
    const int* __restrict__ hist_s, const int* __restrict__ hist_x,
    const int* __restrict__ rr,
    float* __restrict__ outscal)
{
    __shared__ double wred[4];
    int tid = threadIdx.x;
    auto bred = [&](double v) -> double {
        #pragma unroll
        for (int o = 32; o > 0; o >>= 1) v += __shfl_down(v, o);
        __syncthreads();
        if ((tid & 63) == 0) wred[tid >> 6] = v;
        __syncthreads();
        return wred[0] + wred[1] + wred[2] + wred[3];
    };
    double a;
    a = 0; for (int t = tid; t < 1152; t += 256) a += p_vq_s[t];
    double vq_s = bred(a);
    a = 0; for (int t = tid; t < 1152; t += 256) a += p_vq_x[t];
    double vq_x = bred(a);
    a = 0; for (int t = tid; t < 4608; t += 256) a += p_rec_s[t];
    double rec_s = bred(a);
    a = 0; for (int t = tid; t < 4608; t += 256) a += p_rec_x[t];
    double rec_x = bred(a);
    a = 0;
    for (int t = tid; t < 1024; t += 256) {
        double cnt = (double)hist_s[t];
        if (cnt > 0.0) { double p = cnt / (double)NTOK; a += p * log(p + 1e-10); }
    }
    double ent_s = bred(a);
    a = 0;
    for (int t = tid; t < 1024; t += 256) {
        double cnt = (double)hist_x[t];
        if (cnt > 0.0) { double p = cnt / (double)NTOK; a += p * log(p + 1e-10); }
    }
    double ent_x = bred(a);
    if (tid == 0) {
        double total = 0.25 * (vq_s / 4718592.0 + vq_x / 4718592.0);
        double rec = (rr[0] != 0) ? (rec_s / 589824.0 + rec_x / 5308416.0) : 0.0;
        outscal[0] = (float)total;
        outscal[1] = (float)exp(-ent_s);
        outscal[2] = (float)exp(-ent_x);
        outscal[3] = (float)rec;
    }
}

extern "C" void kernel_launch(void* const* d_in, const int* in_sizes, int n_in,
                              void* d_out, int out_size, void* d_ws, size_t ws_size,
                              hipStream_t stream)
{
    const float* cubes  = (const float*)d_in[0];
    const float* s_w1   = (const float*)d_in[1];
    const float* s_b1   = (const float*)d_in[2];
    const float* s_w2   = (const float*)d_in[3];
    const float* s_b2   = (const float*)d_in[4];
    const float* s_fcw  = (const float*)d_in[5];
    const float* s_fcb  = (const float*)d_in[6];
    const float* cb_s   = (const float*)d_in[7];
    const float* s_dfcw = (const float*)d_in[8];
    const float* s_dfcb = (const float*)d_in[9];
    const float* s_dw1  = (const float*)d_in[10];
    const float* s_db1  = (const float*)d_in[11];
    const float* s_dw2  = (const float*)d_in[12];
    const float* s_db2  = (const float*)d_in[13];
    const float* x_w1   = (const float*)d_in[14];
    const float* x_b1   = (const float*)d_in[15];
    const float* x_w2   = (const float*)d_in[16];
    const float* x_b2   = (const float*)d_in[17];
    const float* x_fcw  = (const float*)d_in[18];
    const float* x_fcb  = (const float*)d_in[19];
    const float* cb_x   = (const float*)d_in[20];
    const float* x_dfcw = (const float*)d_in[21];
    const float* x_dfcb = (const float*)d_in[22];
    const float* x_dw1  = (const float*)d_in[23];
    const float* x_db1  = (const float*)d_in[24];
    const float* x_dw2  = (const float*)d_in[25];
    const float* x_db2  = (const float*)d_in[26];
    const int*   rr     = (const int*)d_in[27];

    float* out   = (float*)d_out;
    float* emb_s = out;
    float* emb_x = out + 4718592;
    float* kidx  = out + 9437184;
    float* midx  = out + 9510912;
    float* scal  = out + 9584640;

    char* ws = (char*)d_ws;
    int*    hist_s  = (int*)(ws + 0);
    int*    hist_x  = (int*)(ws + 4096);
    double* cn_s    = (double*)(ws + 8192);
    double* cn_x    = (double*)(ws + 16384);
    double* p_vq_s  = (double*)(ws + 24576);   // 1152 d
    double* p_vq_x  = (double*)(ws + 33792);   // 1152 d
    double* p_rec_s = (double*)(ws + 43008);   // 4608 d
    double* p_rec_x = (double*)(ws + 79872);   // 4608 d
    float*  beff_s  = (float*)(ws + 116736);   // 128 f
    float*  beff_x  = (float*)(ws + 117248);   // 144 f
    float*  weffT_s = (float*)(ws + 117824);   // 64*132 f
    float*  weffT_x = (float*)(ws + 151616);   // 64*148 f
    float*  fcwT_s  = (float*)(ws + 189504);   // 8192 f
    float*  fcwT_x  = (float*)(ws + 222272);   // 9216 f
    float*  sw2T    = (float*)(ws + 259136);   // 768 f
    float*  xw1T    = (float*)(ws + 262208);   // 1152 f
    float*  xw2T    = (float*)(ws + 266816);   // 2304 f
    float*  xdw2T   = (float*)(ws + 276032);   // 1152 f
    float*  cnf_s   = (float*)(ws + 280640);   // 1024 f
    float*  cnf_x   = (float*)(ws + 284736);   // 1024 f (end 288832)

    hipMemsetAsync(d_ws, 0, 8192, stream);     // zero histograms
    k_prep<<<165, 256, 0, stream>>>(cb_s, cb_x, cn_s, cn_x, cnf_s, cnf_x,
                                    s_dw1, s_db1, s_dfcw, s_dfcb, weffT_s, beff_s,
                                    x_dw1, x_db1, x_dfcw, x_dfcb, weffT_x, beff_x,
                                    s_fcw, fcwT_s, x_fcw, fcwT_x,
                                    s_w2, sw2T, x_w1, xw1T, x_w2, xw2T, x_dw2, xdw2T);
    k_spec_enc<<<4608, 256, 0, stream>>>(cubes, s_w1, s_b1, sw2T, s_b2, fcwT_s, s_fcb, emb_s);
    k_spat_enc<<<4608, 256, 0, stream>>>(cubes, xw1T, x_b1, xw2T, x_b2, fcwT_x, x_fcb, emb_x);
    k_vq<<<1152, 512, 0, stream>>>(emb_s, cb_s, cn_s, cnf_s, kidx, hist_s, p_vq_s);
    k_vq<<<1152, 512, 0, stream>>>(emb_x, cb_x, cn_x, cnf_x, midx, hist_x, p_vq_x);
    k_spec_dec<<<4608, 256, 0, stream>>>(emb_s, cubes, weffT_s, beff_s, s_dw2, s_db2, p_rec_s);
    k_spat_dec<<<4608, 256, 0, stream>>>(emb_x, cubes, weffT_x, beff_x, xdw2T, x_db2, p_rec_x);
    k_final<<<1, 256, 0, stream>>>(p_vq_s, p_vq_x, p_rec_s, p_rec_x, hist_s, hist_x, rr, scal);
}

// Round 7
// 2353.440 us; speedup vs baseline: 1.0628x; 1.0628x over previous
//
#include <hip/hip_runtime.h>
#include <math.h>

#define NTOK 73728

__device__ __forceinline__ float gelu_f(float x) {
    return 0.5f * x * (1.0f + erff(x * 0.70710678118654752440f));
}

// ================= prep: norms, fused dec weights, transposes =================
__global__ void __launch_bounds__(256) k_prep(
    const float* __restrict__ cb_s, const float* __restrict__ cb_x,
    double* __restrict__ cn_s, double* __restrict__ cn_x,
    float* __restrict__ cnf_s, float* __restrict__ cnf_x,
    const float* __restrict__ s_dw1, const float* __restrict__ s_db1,
    const float* __restrict__ s_dfcw, const float* __restrict__ s_dfcb,
    float* __restrict__ weffT_s, float* __restrict__ beff_s,
    const float* __restrict__ x_dw1, const float* __restrict__ x_db1,
    const float* __restrict__ x_dfcw, const float* __restrict__ x_dfcb,
    float* __restrict__ weffT_x, float* __restrict__ beff_x,
    const float* __restrict__ s_fcw, float* __restrict__ fcwT_s,
    const float* __restrict__ x_fcw, float* __restrict__ fcwT_x,
    const float* __restrict__ s_w2, float* __restrict__ sw2T,
    const float* __restrict__ x_w1, float* __restrict__ xw1T,
    const float* __restrict__ x_w2, float* __restrict__ xw2T,
    const float* __restrict__ x_dw2, float* __restrict__ xdw2T)
{
    int bid = blockIdx.x, tid = threadIdx.x;
    if (bid < 8) {                     // codebook norms (f64 + f32 copy)
        int i = bid * 256 + tid;
        const float* cb = (i < 1024) ? cb_s : cb_x;
        double* cn = (i < 1024) ? cn_s : cn_x;
        float* cnf = (i < 1024) ? cnf_s : cnf_x;
        int c = i & 1023;
        double s = 0.0;
        for (int k = 0; k < 64; ++k) { double v = (double)cb[c * 64 + k]; s += v * v; }
        cn[c] = s;
        cnf[c] = (float)s;
    } else if (bid < 40) {             // weffT_s
        int idx = (bid - 8) * 256 + tid;
        int o = idx >> 6, d = idx & 63;
        int c = o >> 3, l = o & 7;
        double acc = 0.0;
        for (int ci = 0; ci < 16; ++ci)
            for (int dd = 0; dd < 3; ++dd) {
                int ll = l + dd - 1;
                if (ll < 0 || ll > 7) continue;
                acc += (double)s_dw1[(c * 16 + ci) * 3 + dd] * (double)s_dfcw[(ci * 8 + ll) * 64 + d];
            }
        weffT_s[d * 132 + o] = (float)acc;
        if (o < 4) weffT_s[d * 132 + 128 + o] = 0.f;
        if (d == 0) {
            double bb = (double)s_db1[c];
            for (int ci = 0; ci < 16; ++ci)
                for (int dd = 0; dd < 3; ++dd) {
                    int ll = l + dd - 1;
                    if (ll < 0 || ll > 7) continue;
                    bb += (double)s_dw1[(c * 16 + ci) * 3 + dd] * (double)s_dfcb[ci * 8 + ll];
                }
            beff_s[o] = (float)bb;
        }
    } else if (bid < 76) {             // weffT_x
        int idx = (bid - 40) * 256 + tid;
        int o = idx >> 6, d = idx & 63;
        int c = o / 9, p = o - c * 9;
        int i = p / 3, j = p % 3;
        double acc = 0.0;
        for (int ci = 0; ci < 16; ++ci)
            for (int di = 0; di < 3; ++di) {
                int ii = i + di - 1; if (ii < 0 || ii > 2) continue;
                for (int dj = 0; dj < 3; ++dj) {
                    int jj = j + dj - 1; if (jj < 0 || jj > 2) continue;
                    acc += (double)x_dw1[((c * 16 + ci) * 3 + di) * 3 + dj]
                         * (double)x_dfcw[(ci * 9 + ii * 3 + jj) * 64 + d];
                }
            }
        weffT_x[d * 148 + o] = (float)acc;
        if (o < 4) weffT_x[d * 148 + 144 + o] = 0.f;
        if (d == 0) {
            double bb = (double)x_db1[c];
            for (int ci = 0; ci < 16; ++ci)
                for (int di = 0; di < 3; ++di) {
                    int ii = i + di - 1; if (ii < 0 || ii > 2) continue;
                    for (int dj = 0; dj < 3; ++dj) {
                        int jj = j + dj - 1; if (jj < 0 || jj > 2) continue;
                        bb += (double)x_dw1[((c * 16 + ci) * 3 + di) * 3 + dj]
                            * (double)x_dfcb[ci * 9 + ii * 3 + jj];
                    }
                }
            beff_x[o] = (float)bb;
        }
    } else if (bid < 108) {            // fcwT_s
        int i = (bid - 76) * 256 + tid;
        fcwT_s[i] = s_fcw[(i & 63) * 128 + (i >> 6)];
    } else if (bid < 144) {            // fcwT_x
        int i = (bid - 108) * 256 + tid;
        fcwT_x[i] = x_fcw[(i & 63) * 144 + (i >> 6)];
    } else {                           // small conv-weight transposes
        int i = (bid - 144) * 256 + tid;
        if (i < 768) {
            int c = i & 15, r = i >> 4;
            int ci = r / 3, dd = r % 3;
            sw2T[i] = s_w2[(c * 16 + ci) * 3 + dd];
        } else if (i < 1920) {
            int j = i - 768;
            int c = j & 15, r = j >> 4;
            int ci = r / 9, tap = r % 9;
            xw1T[j] = x_w1[(c * 8 + ci) * 9 + tap];
        } else if (i < 4224) {
            int j = i - 1920;
            int c = j & 15, r = j >> 4;
            int ci = r / 9, tap = r % 9;
            xw2T[j] = x_w2[(c * 16 + ci) * 9 + tap];
        } else {
            int j = i - 4224;
            int co = j & 7, r = j >> 3;
            int ci = r / 9, tap = r % 9;
            xdw2T[j] = x_dw2[(co * 16 + ci) * 9 + tap];
        }
    }
}

// ================= spectral encoder =================
__global__ void __launch_bounds__(256) k_spec_enc(
    const float* __restrict__ cubes,
    const float* __restrict__ w1, const float* __restrict__ b1,
    const float* __restrict__ sw2T, const float* __restrict__ b2,
    const float* __restrict__ fcwT, const float* __restrict__ fcb,
    float* __restrict__ z_out)
{
    __shared__ float S[16 * 8];
    __shared__ float A[16 * 136];
    __shared__ float Bb[16 * 136];
    int tid = threadIdx.x;
    int t = tid >> 4, c = tid & 15;
    if (tid < 128) {
        int tk = tid >> 3, f = tid & 7;
        const float* cu = cubes + ((size_t)blockIdx.x * 16 + tk) * 72 + f * 9;
        float s = 0.f;
        #pragma unroll
        for (int k = 0; k < 9; ++k) s += cu[k];
        S[tk * 8 + f] = s * (1.0f / 9.0f);
    }
    __syncthreads();
    {   // conv1 1->16
        float s0[8];
        *(float4*)&s0[0] = *(const float4*)&S[t * 8];
        *(float4*)&s0[4] = *(const float4*)&S[t * 8 + 4];
        float wa = w1[c * 3 + 0], wb = w1[c * 3 + 1], wc = w1[c * 3 + 2], bb = b1[c];
        #pragma unroll
        for (int l = 0; l < 8; ++l) {
            float v = fmaf(wb, s0[l], bb);
            if (l > 0) v = fmaf(wa, s0[l - 1], v);
            if (l < 7) v = fmaf(wc, s0[l + 1], v);
            A[t * 136 + c * 8 + l] = gelu_f(v);
        }
    }
    __syncthreads();
    {   // conv2 16->16
        float acc[8];
        #pragma unroll
        for (int l = 0; l < 8; ++l) acc[l] = b2[c];
        for (int ci = 0; ci < 16; ++ci) {
            float r[8];
            *(float4*)&r[0] = *(const float4*)&A[t * 136 + ci * 8];
            *(float4*)&r[4] = *(const float4*)&A[t * 136 + ci * 8 + 4];
            float wa = sw2T[(ci * 3 + 0) * 16 + c];
            float wb = sw2T[(ci * 3 + 1) * 16 + c];
            float wc = sw2T[(ci * 3 + 2) * 16 + c];
            #pragma unroll
            for (int l = 0; l < 8; ++l) {
                if (l > 0) acc[l] = fmaf(wa, r[l - 1], acc[l]);
                acc[l] = fmaf(wb, r[l], acc[l]);
                if (l < 7) acc[l] = fmaf(wc, r[l + 1], acc[l]);
            }
        }
        #pragma unroll
        for (int l = 0; l < 8; ++l) Bb[t * 136 + c * 8 + l] = gelu_f(acc[l]);
    }
    __syncthreads();
    {   // fc 128->64
        float4 zv = make_float4(fcb[c * 4 + 0], fcb[c * 4 + 1], fcb[c * 4 + 2], fcb[c * 4 + 3]);
        #pragma unroll 4
        for (int e = 0; e < 128; ++e) {
            float be = Bb[t * 136 + e];
            float4 wv = *(const float4*)(fcwT + (e << 6) + (c << 2));
            zv.x = fmaf(wv.x, be, zv.x);
            zv.y = fmaf(wv.y, be, zv.y);
            zv.z = fmaf(wv.z, be, zv.z);
            zv.w = fmaf(wv.w, be, zv.w);
        }
        *(float4*)(z_out + ((size_t)blockIdx.x * 16 + t) * 64 + c * 4) = zv;
    }
}

// ================= spatial encoder =================
__global__ void __launch_bounds__(256) k_spat_enc(
    const float* __restrict__ cubes,
    const float* __restrict__ xw1T, const float* __restrict__ b1,
    const float* __restrict__ xw2T, const float* __restrict__ b2,
    const float* __restrict__ fcwT, const float* __restrict__ fcb,
    float* __restrict__ z_out)
{
    __shared__ float A[16 * 200];
    __shared__ float Bb[16 * 200];
    int tid = threadIdx.x;
    int t = tid >> 4, c = tid & 15;
    for (int u = tid; u < 1152; u += 256) {
        int tk = u / 72, e = u - tk * 72;
        int ci = e / 9, p = e - ci * 9;
        A[tk * 200 + ci * 12 + p] = cubes[(size_t)blockIdx.x * 1152 + u];
    }
    __syncthreads();
    {   // conv1 8->16
        float acc[9];
        #pragma unroll
        for (int p = 0; p < 9; ++p) acc[p] = b1[c];
        for (int ci = 0; ci < 8; ++ci) {
            float r[12];
            *(float4*)&r[0] = *(const float4*)&A[t * 200 + ci * 12];
            *(float4*)&r[4] = *(const float4*)&A[t * 200 + ci * 12 + 4];
            *(float4*)&r[8] = *(const float4*)&A[t * 200 + ci * 12 + 8];
            float wv[9];
            #pragma unroll
            for (int q = 0; q < 9; ++q) wv[q] = xw1T[(ci * 9 + q) * 16 + c];
            #pragma unroll
            for (int p = 0; p < 9; ++p) {
                int i = p / 3, j = p % 3;
                #pragma unroll
                for (int di = 0; di < 3; ++di) {
                    int ii = i + di - 1; if (ii < 0 || ii > 2) continue;
                    #pragma unroll
                    for (int dj = 0; dj < 3; ++dj) {
                        int jj = j + dj - 1; if (jj < 0 || jj > 2) continue;
                        acc[p] = fmaf(wv[di * 3 + dj], r[ii * 3 + jj], acc[p]);
                    }
                }
            }
        }
        #pragma unroll
        for (int p = 0; p < 9; ++p) Bb[t * 200 + c * 12 + p] = gelu_f(acc[p]);
    }
    __syncthreads();
    {   // conv2 16->16
        float acc[9];
        #pragma unroll
        for (int p = 0; p < 9; ++p) acc[p] = b2[c];
        for (int ci = 0; ci < 16; ++ci) {
            float r[12];
            *(float4*)&r[0] = *(const float4*)&Bb[t * 200 + ci * 12];
            *(float4*)&r[4] = *(const float4*)&Bb[t * 200 + ci * 12 + 4];
            *(float4*)&r[8] = *(const float4*)&Bb[t * 200 + ci * 12 + 8];
            float wv[9];
            #pragma unroll
            for (int q = 0; q < 9; ++q) wv[q] = xw2T[(ci * 9 + q) * 16 + c];
            #pragma unroll
            for (int p = 0; p < 9; ++p) {
                int i = p / 3, j = p % 3;
                #pragma unroll
                for (int di = 0; di < 3; ++di) {
                    int ii = i + di - 1; if (ii < 0 || ii > 2) continue;
                    #pragma unroll
                    for (int dj = 0; dj < 3; ++dj) {
                        int jj = j + dj - 1; if (jj < 0 || jj > 2) continue;
                        acc[p] = fmaf(wv[di * 3 + dj], r[ii * 3 + jj], acc[p]);
                    }
                }
            }
        }
        __syncthreads();
        #pragma unroll
        for (int p = 0; p < 9; ++p) A[t * 200 + c * 12 + p] = gelu_f(acc[p]);
    }
    __syncthreads();
    {   // fc 144->64
        float4 zv = make_float4(fcb[c * 4 + 0], fcb[c * 4 + 1], fcb[c * 4 + 2], fcb[c * 4 + 3]);
        #pragma unroll 4
        for (int e = 0; e < 144; ++e) {
            int ci = e / 9, p = e - ci * 9;
            float be = A[t * 200 + ci * 12 + p];
            float4 wv = *(const float4*)(fcwT + (e << 6) + (c << 2));
            zv.x = fmaf(wv.x, be, zv.x);
            zv.y = fmaf(wv.y, be, zv.y);
            zv.z = fmaf(wv.z, be, zv.z);
            zv.w = fmaf(wv.w, be, zv.w);
        }
        *(float4*)(z_out + ((size_t)blockIdx.x * 16 + t) * 64 + c * 4) = zv;
    }
}

// ===== VQ as register-blocked LDS GEMM: 64 tokens/block, thread = 4 tok x 8 codes =====
__global__ void __launch_bounds__(256) k_vq(
    float* __restrict__ emb, const float* __restrict__ cb,
    const double* __restrict__ cn, const float* __restrict__ cnf,
    float* __restrict__ idx_out, int* __restrict__ hist,
    double* __restrict__ partial)
{
    __shared__ float zL[64][68];        // [tok][k], 17.4 KB
    __shared__ float cbL[128][68];      // [code][k], 34.8 KB (aliased for reduce)
    __shared__ float cnl[128];
    __shared__ int   fi[64];
    __shared__ double wred[4];
    float* pt1 = &cbL[0][0];            // [tok][17] after passes
    float* pt2 = pt1 + 64 * 17;
    int*   pti = (int*)(pt2 + 64 * 17);

    int tid = threadIdx.x;
    int w = tid >> 6, tg = (tid >> 4) & 3, cg = tid & 15;
    size_t blk = blockIdx.x;

    // stage z (64 tokens x 64 dims), coalesced
    for (int u = tid; u < 1024; u += 256) {
        int tok = u >> 4, kq = u & 15;
        *(float4*)&zL[tok][kq * 4] =
            *(const float4*)(emb + (blk * 64 + tok) * 64 + kq * 4);
    }

    float tb1[4], tb2[4]; int ti1[4];
    #pragma unroll
    for (int j = 0; j < 4; ++j) { tb1[j] = 1e30f; tb2[j] = 1e30f; ti1[j] = 0; }
    int tok0 = w * 16 + tg * 4;

    for (int pass = 0; pass < 8; ++pass) {
        __syncthreads();
        for (int u = tid; u < 2048; u += 256) {   // stage 128 codes linearly
            int c = u >> 4, kq = u & 15;
            *(float4*)&cbL[c][kq * 4] =
                *(const float4*)(cb + ((size_t)(pass * 128 + c)) * 64 + kq * 4);
        }
        if (tid < 128) cnl[tid] = cnf[pass * 128 + tid];
        __syncthreads();
        float acc[4][8];
        #pragma unroll
        for (int j = 0; j < 4; ++j)
            #pragma unroll
            for (int i = 0; i < 8; ++i) acc[j][i] = 0.f;
        #pragma unroll 4
        for (int kq = 0; kq < 16; ++kq) {
            float4 zv0 = *(const float4*)&zL[tok0 + 0][kq * 4];
            float4 zv1 = *(const float4*)&zL[tok0 + 1][kq * 4];
            float4 zv2 = *(const float4*)&zL[tok0 + 2][kq * 4];
            float4 zv3 = *(const float4*)&zL[tok0 + 3][kq * 4];
            #pragma unroll
            for (int i = 0; i < 8; ++i) {
                float4 cv = *(const float4*)&cbL[cg + 16 * i][kq * 4];
                acc[0][i] = fmaf(zv0.x, cv.x, acc[0][i]);
                acc[0][i] = fmaf(zv0.y, cv.y, acc[0][i]);
                acc[0][i] = fmaf(zv0.z, cv.z, acc[0][i]);
                acc[0][i] = fmaf(zv0.w, cv.w, acc[0][i]);
                acc[1][i] = fmaf(zv1.x, cv.x, acc[1][i]);
                acc[1][i] = fmaf(zv1.y, cv.y, acc[1][i]);
                acc[1][i] = fmaf(zv1.z, cv.z, acc[1][i]);
                acc[1][i] = fmaf(zv1.w, cv.w, acc[1][i]);
                acc[2][i] = fmaf(zv2.x, cv.x, acc[2][i]);
                acc[2][i] = fmaf(zv2.y, cv.y, acc[2][i]);
                acc[2][i] = fmaf(zv2.z, cv.z, acc[2][i]);
                acc[2][i] = fmaf(zv2.w, cv.w, acc[2][i]);
                acc[3][i] = fmaf(zv3.x, cv.x, acc[3][i]);
                acc[3][i] = fmaf(zv3.y, cv.y, acc[3][i]);
                acc[3][i] = fmaf(zv3.z, cv.z, acc[3][i]);
                acc[3][i] = fmaf(zv3.w, cv.w, acc[3][i]);
            }
        }
        #pragma unroll
        for (int i = 0; i < 8; ++i) {
            int code = pass * 128 + cg + 16 * i;
            float cni = cnl[cg + 16 * i];
            #pragma unroll
            for (int j = 0; j < 4; ++j) {
                float d = fmaf(-2.0f, acc[j][i], cni);
                if (d < tb1[j]) { tb2[j] = tb1[j]; tb1[j] = d; ti1[j] = code; }
                else if (d < tb2[j]) tb2[j] = d;
            }
        }
    }
    __syncthreads();   // done with cbL codes -> reuse as reduce scratch
    #pragma unroll
    for (int j = 0; j < 4; ++j) {
        int tl = tok0 + j;
        pt1[tl * 17 + cg] = tb1[j];
        pt2[tl * 17 + cg] = tb2[j];
        pti[tl * 17 + cg] = ti1[j];
    }
    __syncthreads();
    int l = tid & 63;
    float b1 = 1e30f, b2 = 1e30f; int i1 = 0, flag = 0;
    if (l < 16) {
        int tl = w * 16 + l;
        b1 = pt1[tl * 17]; b2 = pt2[tl * 17]; i1 = pti[tl * 17];
        for (int q = 1; q < 16; ++q) {
            float a1 = pt1[tl * 17 + q], a2 = pt2[tl * 17 + q];
            if (a1 < b1) { b2 = fminf(b1, a2); b1 = a1; i1 = pti[tl * 17 + q]; }
            else b2 = fminf(b2, a1);
        }
        flag = (b2 - b1 < 3e-4f) ? 1 : 0;   // certainty margin (validated R6)
    }
    unsigned long long mask = __ballot(flag != 0);
    while (mask) {            // cooperative exact f64 rescan for rare near-ties
        int tk = __ffsll((long long)mask) - 1; mask &= (mask - 1);
        int tl = w * 16 + tk;
        double bd = 1e300; int bl = 0;
        for (int cc = 0; cc < 16; ++cc) {
            int c = l * 16 + cc;
            const float* cr = cb + ((size_t)c << 6);
            double dot = 0.0;
            #pragma unroll
            for (int k = 0; k < 64; ++k)
                dot = fma((double)zL[tl][k], (double)cr[k], dot);
            double dd = cn[c] - 2.0 * dot;
            if (dd < bd) { bd = dd; bl = c; }
        }
        #pragma unroll
        for (int m = 1; m < 64; m <<= 1) {   // lexicographic (d, idx) min = first-occurrence
            double ob = __shfl_xor(bd, m);
            int oi = __shfl_xor(bl, m);
            if (ob < bd || (ob == bd && oi < bl)) { bd = ob; bl = oi; }
        }
        if (l == tk) i1 = bl;
    }
    if (l < 16) {
        int tl = w * 16 + l;
        fi[tl] = i1;
        idx_out[blk * 64 + tl] = (float)i1;
        atomicAdd(&hist[i1], 1);
    }
    __syncthreads();
    // gather z_q, write emb, vq-loss partial (thread = token x 16-dim chunk)
    {
        int tok = tid >> 2, q = tid & 3;
        int bi = fi[tok];
        const float4* cq4 = (const float4*)(cb + ((size_t)bi << 6) + q * 16);
        float4* zo = (float4*)(emb + (blk * 64 + tok) * 64 + q * 16);
        float vs = 0.f;
        #pragma unroll
        for (int r = 0; r < 4; ++r) {
            float4 qv = cq4[r];
            float4 zv = *(const float4*)&zL[tok][q * 16 + r * 4];
            float dx = zv.x - qv.x, dy = zv.y - qv.y, dz = zv.z - qv.z, dw = zv.w - qv.w;
            vs = fmaf(dx, dx, vs); vs = fmaf(dy, dy, vs);
            vs = fmaf(dz, dz, vs); vs = fmaf(dw, dw, vs);
            zo[r] = qv;
        }
        double s = (double)vs;
        #pragma unroll
        for (int o = 32; o > 0; o >>= 1) s += __shfl_down(s, o);
        if ((tid & 63) == 0) wred[tid >> 6] = s;
        __syncthreads();
        if (tid == 0) partial[blockIdx.x] = wred[0] + wred[1] + wred[2] + wred[3];
    }
}

// ================= spectral decoder + recon loss =================
__global__ void __launch_bounds__(256) k_spec_dec(
    const float* __restrict__ emb, const float* __restrict__ cubes,
    const float* __restrict__ weffT, const float* __restrict__ beff,
    const float* __restrict__ w2, const float* __restrict__ b2,
    double* __restrict__ partial)
{
    __shared__ float Z[16 * 72];
    __shared__ float Bb[16 * 136];
    __shared__ float S[16 * 8];
    __shared__ double wred[4];
    int tid = threadIdx.x;
    int t = tid >> 4, c = tid & 15;
    {
        int tk = tid >> 4, dq = tid & 15;
        *(float4*)&Z[tk * 72 + dq * 4] =
            *(const float4*)(emb + (size_t)blockIdx.x * 1024 + (size_t)tid * 4);
    }
    if (tid < 128) {
        int tk = tid >> 3, f = tid & 7;
        const float* cu = cubes + ((size_t)blockIdx.x * 16 + tk) * 72 + f * 9;
        float s = 0.f;
        #pragma unroll
        for (int k = 0; k < 9; ++k) s += cu[k];
        S[tk * 8 + f] = s * (1.0f / 9.0f);
    }
    __syncthreads();
    float zr[64];
    #pragma unroll
    for (int k = 0; k < 16; ++k) *(float4*)&zr[k * 4] = *(const float4*)&Z[t * 72 + k * 4];
    {
        float4 a0 = make_float4(0.f, 0.f, 0.f, 0.f);
        float4 a1 = make_float4(0.f, 0.f, 0.f, 0.f);
        #pragma unroll 8
        for (int k = 0; k < 64; ++k) {
            float zk = zr[k];
            float4 w0 = *(const float4*)(weffT + k * 132 + (c << 2));
            float4 w1v = *(const float4*)(weffT + k * 132 + 64 + (c << 2));
            a0.x = fmaf(w0.x, zk, a0.x); a0.y = fmaf(w0.y, zk, a0.y);
            a0.z = fmaf(w0.z, zk, a0.z); a0.w = fmaf(w0.w, zk, a0.w);
            a1.x = fmaf(w1v.x, zk, a1.x); a1.y = fmaf(w1v.y, zk, a1.y);
            a1.z = fmaf(w1v.z, zk, a1.z); a1.w = fmaf(w1v.w, zk, a1.w);
        }
        int o0 = c << 2, o1 = 64 + (c << 2);
        float4 g0 = make_float4(gelu_f(a0.x + beff[o0 + 0]), gelu_f(a0.y + beff[o0 + 1]),
                                gelu_f(a0.z + beff[o0 + 2]), gelu_f(a0.w + beff[o0 + 3]));
        float4 g1 = make_float4(gelu_f(a1.x + beff[o1 + 0]), gelu_f(a1.y + beff[o1 + 1]),
                                gelu_f(a1.z + beff[o1 + 2]), gelu_f(a1.w + beff[o1 + 3]));
        *(float4*)&Bb[t * 136 + o0] = g0;
        *(float4*)&Bb[t * 136 + o1] = g1;
    }
    __syncthreads();
    float acc2 = 0.f;
    {   // conv2 16->1 + loss
        int h = c >> 3, pos = c & 7;
        float a = (h == 0) ? b2[0] : 0.f;
        for (int ci = h * 8; ci < h * 8 + 8; ++ci) {
            const float* w = w2 + ci * 3;
            const float* hb = &Bb[t * 136 + ci * 8];
            if (pos > 0) a = fmaf(w[0], hb[pos - 1], a);
            a = fmaf(w[1], hb[pos], a);
            if (pos < 7) a = fmaf(w[2], hb[pos + 1], a);
        }
        a += __shfl_xor(a, 8);
        if (h == 0) { float df = a - S[t * 8 + pos]; acc2 = df * df; }
    }
    double s = (double)acc2;
    #pragma unroll
    for (int o = 32; o > 0; o >>= 1) s += __shfl_down(s, o);
    if ((tid & 63) == 0) wred[tid >> 6] = s;
    __syncthreads();
    if (tid == 0) partial[blockIdx.x] = wred[0] + wred[1] + wred[2] + wred[3];
}

// ================= spatial decoder + recon loss =================
__global__ void __launch_bounds__(256) k_spat_dec(
    const float* __restrict__ emb, const float* __restrict__ cubes,
    const float* __restrict__ weffT, const float* __restrict__ beff,
    const float* __restrict__ xdw2T, const float* __restrict__ b2,
    double* __restrict__ partial)
{
    __shared__ float Z[16 * 72];
    __shared__ float H[16 * 200];
    __shared__ float T[16 * 104];
    __shared__ double wred[4];
    int tid = threadIdx.x;
    int t = tid >> 4, c = tid & 15;
    {
        int tk = tid >> 4, dq = tid & 15;
        *(float4*)&Z[tk * 72 + dq * 4] =
            *(const float4*)(emb + (size_t)blockIdx.x * 1024 + (size_t)tid * 4);
    }
    for (int u = tid; u < 1152; u += 256) {
        int tk = u / 72, e = u - tk * 72;
        int ci = e / 9, p = e - ci * 9;
        T[tk * 104 + ci * 12 + p] = cubes[(size_t)blockIdx.x * 1152 + u];
    }
    __syncthreads();
    float zr[64];
    #pragma unroll
    for (int k = 0; k < 16; ++k) *(float4*)&zr[k * 4] = *(const float4*)&Z[t * 72 + k * 4];
    {
        float4 a0 = make_float4(0.f, 0.f, 0.f, 0.f);
        float4 a1 = make_float4(0.f, 0.f, 0.f, 0.f);
        float4 a2 = make_float4(0.f, 0.f, 0.f, 0.f);
        #pragma unroll 8
        for (int k = 0; k < 64; ++k) {
            float zk = zr[k];
            float4 w0 = *(const float4*)(weffT + k * 148 + (c << 2));
            float4 w1v = *(const float4*)(weffT + k * 148 + 64 + (c << 2));
            float4 w2v = *(const float4*)(weffT + k * 148 + 128 + (c << 2));
            a0.x = fmaf(w0.x, zk, a0.x); a0.y = fmaf(w0.y, zk, a0.y);
            a0.z = fmaf(w0.z, zk, a0.z); a0.w = fmaf(w0.w, zk, a0.w);
            a1.x = fmaf(w1v.x, zk, a1.x); a1.y = fmaf(w1v.y, zk, a1.y);
            a1.z = fmaf(w1v.z, zk, a1.z); a1.w = fmaf(w1v.w, zk, a1.w);
            a2.x = fmaf(w2v.x, zk, a2.x); a2.y = fmaf(w2v.y, zk, a2.y);
            a2.z = fmaf(w2v.z, zk, a2.z); a2.w = fmaf(w2v.w, zk, a2.w);
        }
        float av[12] = {a0.x, a0.y, a0.z, a0.w, a1.x, a1.y, a1.z, a1.w, a2.x, a2.y, a2.z, a2.w};
        #pragma unroll
        for (int q = 0; q < 12; ++q) {
            int o = (c << 2) + ((q >> 2) << 6) + (q & 3);
            int ch = o / 9, p = o - ch * 9;
            H[t * 200 + ch * 12 + p] = gelu_f(av[q] + beff[o]);
        }
    }
    __syncthreads();
    float acc2 = 0.f;
    {   // conv2 16->8 + loss
        int co = c >> 1, h = c & 1;
        float accp[9];
        #pragma unroll
        for (int p = 0; p < 9; ++p) accp[p] = (h == 0) ? b2[co] : 0.f;
        for (int ci = h * 8; ci < h * 8 + 8; ++ci) {
            float r[12];
            *(float4*)&r[0] = *(const float4*)&H[t * 200 + ci * 12];
            *(float4*)&r[4] = *(const float4*)&H[t * 200 + ci * 12 + 4];
            *(float4*)&r[8] = *(const float4*)&H[t * 200 + ci * 12 + 8];
            float wv[9];
            #pragma unroll
            for (int q = 0; q < 9; ++q) wv[q] = xdw2T[(ci * 9 + q) * 8 + co];
            #pragma unroll
            for (int p = 0; p < 9; ++p) {
                int i = p / 3, j = p % 3;
                #pragma unroll
                for (int di = 0; di < 3; ++di) {
                    int ii = i + di - 1; if (ii < 0 || ii > 2) continue;
                    #pragma unroll
                    for (int dj = 0; dj < 3; ++dj) {
                        int jj = j + dj - 1; if (jj < 0 || jj > 2) continue;
                        accp[p] = fmaf(wv[di * 3 + dj], r[ii * 3 + jj], accp[p]);
                    }
                }
            }
        }
        #pragma unroll
        for (int p = 0; p < 9; ++p) {
            float tot = accp[p] + __shfl_xor(accp[p], 1);
            if (h == 0) { float df = tot - T[t * 104 + co * 12 + p]; acc2 = fmaf(df, df, acc2); }
        }
    }
    double s = (double)acc2;
    #pragma unroll
    for (int o = 32; o > 0; o >>= 1) s += __shfl_down(s, o);
    if ((tid & 63) == 0) wred[tid >> 6] = s;
    __syncthreads();
    if (tid == 0) partial[blockIdx.x] = wred[0] + wred[1] + wred[2] + wred[3];
}

// ================= finalize scalars =================
__global__ void __launch_bounds__(256) k_final(
    const double* __restrict__ p_vq_s, const double* __restrict__ p_vq_x,
    const double* __restrict__ p_rec_s, const double* __restrict__ p_rec_x,
    const int* __restrict__ hist_s, const int* __restrict__ hist_x,
    const int* __restrict__ rr,
    float* __restrict__ outscal)
{
    __shared__ double wred[4];
    int tid = threadIdx.x;
    auto bred = [&](double v) -> double {
        #pragma unroll
        for (int o = 32; o > 0; o >>= 1) v += __shfl_down(v, o);
        __syncthreads();
        if ((tid & 63) == 0) wred[tid >> 6] = v;
        __syncthreads();
        return wred[0] + wred[1] + wred[2] + wred[3];
    };
    double a;
    a = 0; for (int t = tid; t < 1152; t += 256) a += p_vq_s[t];
    double vq_s = bred(a);
    a = 0; for (int t = tid; t < 1152; t += 256) a += p_vq_x[t];
    double vq_x = bred(a);
    a = 0; for (int t = tid; t < 4608; t += 256) a += p_rec_s[t];
    double rec_s = bred(a);
    a = 0; for (int t = tid; t < 4608; t += 256) a += p_rec_x[t];
    double rec_x = bred(a);
    a = 0;
    for (int t = tid; t < 1024; t += 256) {
        double cnt = (double)hist_s[t];
        if (cnt > 0.0) { double p = cnt / (double)NTOK; a += p * log(p + 1e-10); }
    }
    double ent_s = bred(a);
    a = 0;
    for (int t = tid; t < 1024; t += 256) {
        double cnt = (double)hist_x[t];
        if (cnt > 0.0) { double p = cnt / (double)NTOK; a += p * log(p + 1e-10); }
    }
    double ent_x = bred(a);
    if (tid == 0) {
        double total = 0.25 * (vq_s / 4718592.0 + vq_x / 4718592.0);
        double rec = (rr[0] != 0) ? (rec_s / 589824.0 + rec_x / 5308416.0) : 0.0;
        outscal[0] = (float)total;
        outscal[1] = (float)exp(-ent_s);
        outscal[2] = (float)exp(-ent_x);
        outscal[3] = (float)rec;
    }
}

extern "C" void kernel_launch(void* const* d_in, const int* in_sizes, int n_in,
                              void* d_out, int out_size, void* d_ws, size_t ws_size,
                              hipStream_t stream)
{
    const float* cubes  = (const float*)d_in[0];
    const float* s_w1   = (const float*)d_in[1];
    const float* s_b1   = (const float*)d_in[2];
    const float* s_w2   = (const float*)d_in[3];
    const float* s_b2   = (const float*)d_in[4];
    const float* s_fcw  = (const float*)d_in[5];
    const float* s_fcb  = (const float*)d_in[6];
    const float* cb_s   = (const float*)d_in[7];
    const float* s_dfcw = (const float*)d_in[8];
    const float* s_dfcb = (const float*)d_in[9];
    const float* s_dw1  = (const float*)d_in[10];
    const float* s_db1  = (const float*)d_in[11];
    const float* s_dw2  = (const float*)d_in[12];
    const float* s_db2  = (const float*)d_in[13];
    const float* x_w1   = (const float*)d_in[14];
    const float* x_b1   = (const float*)d_in[15];
    const float* x_w2   = (const float*)d_in[16];
    const float* x_b2   = (const float*)d_in[17];
    const float* x_fcw  = (const float*)d_in[18];
    const float* x_fcb  = (const float*)d_in[19];
    const float* cb_x   = (const float*)d_in[20];
    const float* x_dfcw = (const float*)d_in[21];
    const float* x_dfcb = (const float*)d_in[22];
    const float* x_dw1  = (const float*)d_in[23];
    const float* x_db1  = (const float*)d_in[24];
    const float* x_dw2  = (const float*)d_in[25];
    const float* x_db2  = (const float*)d_in[26];
    const int*   rr     = (const int*)d_in[27];

    float* out   = (float*)d_out;
    float* emb_s = out;
    float* emb_x = out + 4718592;
    float* kidx  = out + 9437184;
    float* midx  = out + 9510912;
    float* scal  = out + 9584640;

    char* ws = (char*)d_ws;
    int*    hist_s  = (int*)(ws + 0);
    int*    hist_x  = (int*)(ws + 4096);
    double* cn_s    = (double*)(ws + 8192);
    double* cn_x    = (double*)(ws + 16384);
    double* p_vq_s  = (double*)(ws + 24576);   // 1152 d
    double* p_vq_x  = (double*)(ws + 33792);   // 1152 d
    double* p_rec_s = (double*)(ws + 43008);   // 4608 d
    double* p_rec_x = (double*)(ws + 79872);   // 4608 d
    float*  beff_s  = (float*)(ws + 116736);   // 128 f
    float*  beff_x  = (float*)(ws + 117248);   // 144 f
    float*  weffT_s = (float*)(ws + 117824);   // 64*132 f
    float*  weffT_x = (float*)(ws + 151616);   // 64*148 f
    float*  fcwT_s  = (float*)(ws + 189504);   // 8192 f
    float*  fcwT_x  = (float*)(ws + 222272);   // 9216 f
    float*  sw2T    = (float*)(ws + 259136);   // 768 f
    float*  xw1T    = (float*)(ws + 262208);   // 1152 f
    float*  xw2T    = (float*)(ws + 266816);   // 2304 f
    float*  xdw2T   = (float*)(ws + 276032);   // 1152 f
    float*  cnf_s   = (float*)(ws + 280640);   // 1024 f
    float*  cnf_x   = (float*)(ws + 284736);   // 1024 f (end 288832)

    hipMemsetAsync(d_ws, 0, 8192, stream);     // zero histograms
    k_prep<<<165, 256, 0, stream>>>(cb_s, cb_x, cn_s, cn_x, cnf_s, cnf_x,
                                    s_dw1, s_db1, s_dfcw, s_dfcb, weffT_s, beff_s,
                                    x_dw1, x_db1, x_dfcw, x_dfcb, weffT_x, beff_x,
                                    s_fcw, fcwT_s, x_fcw, fcwT_x,
                                    s_w2, sw2T, x_w1, xw1T, x_w2, xw2T, x_dw2, xdw2T);
    k_spec_enc<<<4608, 256, 0, stream>>>(cubes, s_w1, s_b1, sw2T, s_b2, fcwT_s, s_fcb, emb_s);
    k_spat_enc<<<4608, 256, 0, stream>>>(cubes, xw1T, x_b1, xw2T, x_b2, fcwT_x, x_fcb, emb_x);
    k_vq<<<1152, 256, 0, stream>>>(emb_s, cb_s, cn_s, cnf_s, kidx, hist_s, p_vq_s);
    k_vq<<<1152, 256, 0, stream>>>(emb_x, cb_x, cn_x, cnf_x, midx, hist_x, p_vq_x);
    k_spec_dec<<<4608, 256, 0, stream>>>(emb_s, cubes, weffT_s, beff_s, s_dw2, s_db2, p_rec_s);
    k_spat_dec<<<4608, 256, 0, stream>>>(emb_x, cubes, weffT_x, beff_x, xdw2T, x_db2, p_rec_x);
    k_final<<<1, 256, 0, stream>>>(p_vq_s, p_vq_x, p_rec_s, p_rec_x, hist_s, hist_x, rr, scal);
}

// Round 8
// 1027.901 us; speedup vs baseline: 2.4333x; 2.2896x over previous
//
#include <hip/hip_runtime.h>
#include <math.h>

#define NTOK 73728

__device__ __forceinline__ float gelu_f(float x) {
    return 0.5f * x * (1.0f + erff(x * 0.70710678118654752440f));
}

// ================= prep: norms, fused dec weights, transposes =================
__global__ void __launch_bounds__(256) k_prep(
    const float* __restrict__ cb_s, const float* __restrict__ cb_x,
    double* __restrict__ cn_s, double* __restrict__ cn_x,
    const float* __restrict__ s_dw1, const float* __restrict__ s_db1,
    const float* __restrict__ s_dfcw, const float* __restrict__ s_dfcb,
    float* __restrict__ weffT_s, float* __restrict__ beff_s,
    const float* __restrict__ x_dw1, const float* __restrict__ x_db1,
    const float* __restrict__ x_dfcw, const float* __restrict__ x_dfcb,
    float* __restrict__ weffT_x, float* __restrict__ beff_x,
    const float* __restrict__ s_fcw, float* __restrict__ fcwT_s,
    const float* __restrict__ x_fcw, float* __restrict__ fcwT_x,
    const float* __restrict__ s_w2, float* __restrict__ sw2T,
    const float* __restrict__ x_w1, float* __restrict__ xw1T,
    const float* __restrict__ x_w2, float* __restrict__ xw2T,
    const float* __restrict__ x_dw2, float* __restrict__ xdw2T)
{
    int bid = blockIdx.x, tid = threadIdx.x;
    if (bid < 8) {                     // codebook norms (f64)
        int i = bid * 256 + tid;
        const float* cb = (i < 1024) ? cb_s : cb_x;
        double* cn = (i < 1024) ? cn_s : cn_x;
        int c = i & 1023;
        double s = 0.0;
        for (int k = 0; k < 64; ++k) { double v = (double)cb[c * 64 + k]; s += v * v; }
        cn[c] = s;
    } else if (bid < 40) {             // weffT_s
        int idx = (bid - 8) * 256 + tid;
        int o = idx >> 6, d = idx & 63;
        int c = o >> 3, l = o & 7;
        double acc = 0.0;
        for (int ci = 0; ci < 16; ++ci)
            for (int dd = 0; dd < 3; ++dd) {
                int ll = l + dd - 1;
                if (ll < 0 || ll > 7) continue;
                acc += (double)s_dw1[(c * 16 + ci) * 3 + dd] * (double)s_dfcw[(ci * 8 + ll) * 64 + d];
            }
        weffT_s[d * 132 + o] = (float)acc;
        if (o < 4) weffT_s[d * 132 + 128 + o] = 0.f;
        if (d == 0) {
            double bb = (double)s_db1[c];
            for (int ci = 0; ci < 16; ++ci)
                for (int dd = 0; dd < 3; ++dd) {
                    int ll = l + dd - 1;
                    if (ll < 0 || ll > 7) continue;
                    bb += (double)s_dw1[(c * 16 + ci) * 3 + dd] * (double)s_dfcb[ci * 8 + ll];
                }
            beff_s[o] = (float)bb;
        }
    } else if (bid < 76) {             // weffT_x
        int idx = (bid - 40) * 256 + tid;
        int o = idx >> 6, d = idx & 63;
        int c = o / 9, p = o - c * 9;
        int i = p / 3, j = p % 3;
        double acc = 0.0;
        for (int ci = 0; ci < 16; ++ci)
            for (int di = 0; di < 3; ++di) {
                int ii = i + di - 1; if (ii < 0 || ii > 2) continue;
                for (int dj = 0; dj < 3; ++dj) {
                    int jj = j + dj - 1; if (jj < 0 || jj > 2) continue;
                    acc += (double)x_dw1[((c * 16 + ci) * 3 + di) * 3 + dj]
                         * (double)x_dfcw[(ci * 9 + ii * 3 + jj) * 64 + d];
                }
            }
        weffT_x[d * 148 + o] = (float)acc;
        if (o < 4) weffT_x[d * 148 + 144 + o] = 0.f;
        if (d == 0) {
            double bb = (double)x_db1[c];
            for (int ci = 0; ci < 16; ++ci)
                for (int di = 0; di < 3; ++di) {
                    int ii = i + di - 1; if (ii < 0 || ii > 2) continue;
                    for (int dj = 0; dj < 3; ++dj) {
                        int jj = j + dj - 1; if (jj < 0 || jj > 2) continue;
                        bb += (double)x_dw1[((c * 16 + ci) * 3 + di) * 3 + dj]
                            * (double)x_dfcb[ci * 9 + ii * 3 + jj];
                    }
                }
            beff_x[o] = (float)bb;
        }
    } else if (bid < 108) {            // fcwT_s
        int i = (bid - 76) * 256 + tid;
        fcwT_s[i] = s_fcw[(i & 63) * 128 + (i >> 6)];
    } else if (bid < 144) {            // fcwT_x
        int i = (bid - 108) * 256 + tid;
        fcwT_x[i] = x_fcw[(i & 63) * 144 + (i >> 6)];
    } else {                           // small conv-weight transposes
        int i = (bid - 144) * 256 + tid;
        if (i < 768) {
            int c = i & 15, r = i >> 4;
            int ci = r / 3, dd = r % 3;
            sw2T[i] = s_w2[(c * 16 + ci) * 3 + dd];
        } else if (i < 1920) {
            int j = i - 768;
            int c = j & 15, r = j >> 4;
            int ci = r / 9, tap = r % 9;
            xw1T[j] = x_w1[(c * 8 + ci) * 9 + tap];
        } else if (i < 4224) {
            int j = i - 1920;
            int c = j & 15, r = j >> 4;
            int ci = r / 9, tap = r % 9;
            xw2T[j] = x_w2[(c * 16 + ci) * 9 + tap];
        } else {
            int j = i - 4224;
            int co = j & 7, r = j >> 3;
            int ci = r / 9, tap = r % 9;
            xdw2T[j] = x_dw2[(co * 16 + ci) * 9 + tap];
        }
    }
}

// ================= merged encoders: blocks [0,4608) spectral, [4608,9216) spatial =================
__global__ void __launch_bounds__(256) k_enc(
    const float* __restrict__ cubes,
    const float* __restrict__ s_w1, const float* __restrict__ s_b1,
    const float* __restrict__ sw2T, const float* __restrict__ s_b2,
    const float* __restrict__ fcwT_s, const float* __restrict__ s_fcb,
    float* __restrict__ emb_s,
    const float* __restrict__ xw1T, const float* __restrict__ x_b1,
    const float* __restrict__ xw2T, const float* __restrict__ x_b2,
    const float* __restrict__ fcwT_x, const float* __restrict__ x_fcb,
    float* __restrict__ emb_x)
{
    __shared__ float U[6528];
    int tid = threadIdx.x;
    int t = tid >> 4, c = tid & 15;
    if (blockIdx.x < 4608) {
        // ---------------- spectral ----------------
        int b = blockIdx.x;
        float* S = U;            // 128
        float* A = U + 128;      // 2176
        float* Bb = U + 2304;    // 2176
        if (tid < 128) {
            int tk = tid >> 3, f = tid & 7;
            const float* cu = cubes + ((size_t)b * 16 + tk) * 72 + f * 9;
            float s = 0.f;
            #pragma unroll
            for (int k = 0; k < 9; ++k) s += cu[k];
            S[tk * 8 + f] = s * (1.0f / 9.0f);
        }
        __syncthreads();
        {   // conv1 1->16
            float s0[8];
            *(float4*)&s0[0] = *(const float4*)&S[t * 8];
            *(float4*)&s0[4] = *(const float4*)&S[t * 8 + 4];
            float wa = s_w1[c * 3 + 0], wb = s_w1[c * 3 + 1], wc = s_w1[c * 3 + 2], bb = s_b1[c];
            #pragma unroll
            for (int l = 0; l < 8; ++l) {
                float v = fmaf(wb, s0[l], bb);
                if (l > 0) v = fmaf(wa, s0[l - 1], v);
                if (l < 7) v = fmaf(wc, s0[l + 1], v);
                A[t * 136 + c * 8 + l] = gelu_f(v);
            }
        }
        __syncthreads();
        {   // conv2 16->16
            float acc[8];
            #pragma unroll
            for (int l = 0; l < 8; ++l) acc[l] = s_b2[c];
            for (int ci = 0; ci < 16; ++ci) {
                float r[8];
                *(float4*)&r[0] = *(const float4*)&A[t * 136 + ci * 8];
                *(float4*)&r[4] = *(const float4*)&A[t * 136 + ci * 8 + 4];
                float wa = sw2T[(ci * 3 + 0) * 16 + c];
                float wb = sw2T[(ci * 3 + 1) * 16 + c];
                float wc = sw2T[(ci * 3 + 2) * 16 + c];
                #pragma unroll
                for (int l = 0; l < 8; ++l) {
                    if (l > 0) acc[l] = fmaf(wa, r[l - 1], acc[l]);
                    acc[l] = fmaf(wb, r[l], acc[l]);
                    if (l < 7) acc[l] = fmaf(wc, r[l + 1], acc[l]);
                }
            }
            #pragma unroll
            for (int l = 0; l < 8; ++l) Bb[t * 136 + c * 8 + l] = gelu_f(acc[l]);
        }
        __syncthreads();
        {   // fc 128->64
            float4 zv = make_float4(s_fcb[c * 4 + 0], s_fcb[c * 4 + 1], s_fcb[c * 4 + 2], s_fcb[c * 4 + 3]);
            #pragma unroll 4
            for (int e = 0; e < 128; ++e) {
                float be = Bb[t * 136 + e];
                float4 wv = *(const float4*)(fcwT_s + (e << 6) + (c << 2));
                zv.x = fmaf(wv.x, be, zv.x);
                zv.y = fmaf(wv.y, be, zv.y);
                zv.z = fmaf(wv.z, be, zv.z);
                zv.w = fmaf(wv.w, be, zv.w);
            }
            *(float4*)(emb_s + ((size_t)b * 16 + t) * 64 + c * 4) = zv;
        }
    } else {
        // ---------------- spatial ----------------
        int b = blockIdx.x - 4608;
        float* A = U;            // 3200
        float* Bb = U + 3200;    // 3200
        for (int u = tid; u < 1152; u += 256) {
            int tk = u / 72, e = u - tk * 72;
            int ci = e / 9, p = e - ci * 9;
            A[tk * 200 + ci * 12 + p] = cubes[(size_t)b * 1152 + u];
        }
        __syncthreads();
        {   // conv1 8->16
            float acc[9];
            #pragma unroll
            for (int p = 0; p < 9; ++p) acc[p] = x_b1[c];
            for (int ci = 0; ci < 8; ++ci) {
                float r[12];
                *(float4*)&r[0] = *(const float4*)&A[t * 200 + ci * 12];
                *(float4*)&r[4] = *(const float4*)&A[t * 200 + ci * 12 + 4];
                *(float4*)&r[8] = *(const float4*)&A[t * 200 + ci * 12 + 8];
                float wv[9];
                #pragma unroll
                for (int q = 0; q < 9; ++q) wv[q] = xw1T[(ci * 9 + q) * 16 + c];
                #pragma unroll
                for (int p = 0; p < 9; ++p) {
                    int i = p / 3, j = p % 3;
                    #pragma unroll
                    for (int di = 0; di < 3; ++di) {
                        int ii = i + di - 1; if (ii < 0 || ii > 2) continue;
                        #pragma unroll
                        for (int dj = 0; dj < 3; ++dj) {
                            int jj = j + dj - 1; if (jj < 0 || jj > 2) continue;
                            acc[p] = fmaf(wv[di * 3 + dj], r[ii * 3 + jj], acc[p]);
                        }
                    }
                }
            }
            #pragma unroll
            for (int p = 0; p < 9; ++p) Bb[t * 200 + c * 12 + p] = gelu_f(acc[p]);
        }
        __syncthreads();
        {   // conv2 16->16
            float acc[9];
            #pragma unroll
            for (int p = 0; p < 9; ++p) acc[p] = x_b2[c];
            for (int ci = 0; ci < 16; ++ci) {
                float r[12];
                *(float4*)&r[0] = *(const float4*)&Bb[t * 200 + ci * 12];
                *(float4*)&r[4] = *(const float4*)&Bb[t * 200 + ci * 12 + 4];
                *(float4*)&r[8] = *(const float4*)&Bb[t * 200 + ci * 12 + 8];
                float wv[9];
                #pragma unroll
                for (int q = 0; q < 9; ++q) wv[q] = xw2T[(ci * 9 + q) * 16 + c];
                #pragma unroll
                for (int p = 0; p < 9; ++p) {
                    int i = p / 3, j = p % 3;
                    #pragma unroll
                    for (int di = 0; di < 3; ++di) {
                        int ii = i + di - 1; if (ii < 0 || ii > 2) continue;
                        #pragma unroll
                        for (int dj = 0; dj < 3; ++dj) {
                            int jj = j + dj - 1; if (jj < 0 || jj > 2) continue;
                            acc[p] = fmaf(wv[di * 3 + dj], r[ii * 3 + jj], acc[p]);
                        }
                    }
                }
            }
            __syncthreads();
            #pragma unroll
            for (int p = 0; p < 9; ++p) A[t * 200 + c * 12 + p] = gelu_f(acc[p]);
        }
        __syncthreads();
        {   // fc 144->64
            float4 zv = make_float4(x_fcb[c * 4 + 0], x_fcb[c * 4 + 1], x_fcb[c * 4 + 2], x_fcb[c * 4 + 3]);
            #pragma unroll 4
            for (int e = 0; e < 144; ++e) {
                int ci = e / 9, p = e - ci * 9;
                float be = A[t * 200 + ci * 12 + p];
                float4 wv = *(const float4*)(fcwT_x + (e << 6) + (c << 2));
                zv.x = fmaf(wv.x, be, zv.x);
                zv.y = fmaf(wv.y, be, zv.y);
                zv.z = fmaf(wv.z, be, zv.z);
                zv.w = fmaf(wv.w, be, zv.w);
            }
            *(float4*)(emb_x + ((size_t)b * 16 + t) * 64 + c * 4) = zv;
        }
    }
}

// ===== merged VQ (R3 structure): blocks [0,1152) spectral, [1152,2304) spatial =====
// 64 tokens/block, 4 waves x 256-code chunks, SGPR codebook loads, f64 compare.
__global__ void __launch_bounds__(256) k_vq(
    float* __restrict__ emb_s, float* __restrict__ emb_x,
    const float* __restrict__ cb_s, const float* __restrict__ cb_x,
    const double* __restrict__ cn_s, const double* __restrict__ cn_x,
    float* __restrict__ kidx, float* __restrict__ midx,
    int* __restrict__ hist_s, int* __restrict__ hist_x,
    double* __restrict__ p_vq_s, double* __restrict__ p_vq_x)
{
    __shared__ double pbest[4][64];
    __shared__ int pidx[4][64];
    __shared__ int lh[1024];
    int blk = blockIdx.x;
    int path = (blk >= 1152) ? 1 : 0;
    int b = blk - (path << 10) - (path << 7);          // blk - path*1152
    float* emb = path ? emb_x : emb_s;
    const float* cb = path ? cb_x : cb_s;
    const double* cn = path ? cn_x : cn_s;
    float* idx_out = path ? midx : kidx;
    int* hist = path ? hist_x : hist_s;
    double* partial = path ? p_vq_x : p_vq_s;

    int tid = threadIdx.x;
    int w = tid >> 6, l = tid & 63;
    for (int u = tid; u < 1024; u += 256) lh[u] = 0;
    size_t n = (size_t)b * 64 + l;
    float z[64];
    {
        const float4* zp = (const float4*)(emb + n * 64);
        #pragma unroll
        for (int k = 0; k < 16; ++k) *(float4*)&z[k * 4] = zp[k];
    }
    // force wave-uniform base -> SGPR codebook pointer -> s_load + v_fmac(sgpr)
    int base = __builtin_amdgcn_readfirstlane(w << 8);
    const float* crb = cb + ((size_t)base << 6);
    const double* cnb = cn + base;
    double best = 1e300; int bi = base;
    for (int cc = 0; cc < 256; ++cc) {
        const float* cr = crb + (cc << 6);
        float d0 = 0.f, d1 = 0.f, d2 = 0.f, d3 = 0.f;
        #pragma unroll
        for (int k = 0; k < 64; k += 4) {
            d0 = fmaf(z[k + 0], cr[k + 0], d0);
            d1 = fmaf(z[k + 1], cr[k + 1], d1);
            d2 = fmaf(z[k + 2], cr[k + 2], d2);
            d3 = fmaf(z[k + 3], cr[k + 3], d3);
        }
        float dot = (d0 + d1) + (d2 + d3);
        double dd = cnb[cc] - 2.0 * (double)dot;
        if (dd < best) { best = dd; bi = base + cc; }   // strict <: first-index
    }
    pbest[w][l] = best; pidx[w][l] = bi;
    __syncthreads();
    if (w == 0) {
        double bB = pbest[0][l]; int bj = pidx[0][l];
        #pragma unroll
        for (int q = 1; q < 4; ++q) {                   // ascending chunks, strict <
            double d = pbest[q][l];
            if (d < bB) { bB = d; bj = pidx[q][l]; }
        }
        idx_out[n] = (float)bj;
        float qv[64];
        {
            const float4* cq = (const float4*)(cb + ((size_t)bj << 6));
            #pragma unroll
            for (int k = 0; k < 16; ++k) *(float4*)&qv[k * 4] = cq[k];
        }
        float vs = 0.f;
        #pragma unroll
        for (int k = 0; k < 64; ++k) { float df = z[k] - qv[k]; vs = fmaf(df, df, vs); }
        float4* zo = (float4*)(emb + n * 64);
        #pragma unroll
        for (int k = 0; k < 16; ++k) zo[k] = *(float4*)&qv[k * 4];
        atomicAdd(&lh[bj], 1);
        double s = (double)vs;
        #pragma unroll
        for (int o = 32; o > 0; o >>= 1) s += __shfl_down(s, o);
        if (l == 0) partial[b] = s;
    }
    __syncthreads();
    for (int u = tid; u < 1024; u += 256) if (lh[u] > 0) atomicAdd(&hist[u], lh[u]);
}

// ================= merged decoders: blocks [0,4608) spectral, [4608,9216) spatial =================
__global__ void __launch_bounds__(256) k_dec(
    const float* __restrict__ emb_s, const float* __restrict__ emb_x,
    const float* __restrict__ cubes,
    const float* __restrict__ weffT_s, const float* __restrict__ beff_s,
    const float* __restrict__ s_dw2, const float* __restrict__ s_db2,
    const float* __restrict__ weffT_x, const float* __restrict__ beff_x,
    const float* __restrict__ xdw2T, const float* __restrict__ x_db2,
    double* __restrict__ p_rec_s, double* __restrict__ p_rec_x)
{
    __shared__ float U[6016];
    __shared__ double wred[4];
    int tid = threadIdx.x;
    int t = tid >> 4, c = tid & 15;
    if (blockIdx.x < 4608) {
        // ---------------- spectral ----------------
        int b = blockIdx.x;
        float* Z = U;            // 1152 (stride 72)
        float* Bb = U + 1152;    // 2176
        float* S = U + 3328;     // 128
        {
            int tk = tid >> 4, dq = tid & 15;
            *(float4*)&Z[tk * 72 + dq * 4] =
                *(const float4*)(emb_s + (size_t)b * 1024 + (size_t)tid * 4);
        }
        if (tid < 128) {
            int tk = tid >> 3, f = tid & 7;
            const float* cu = cubes + ((size_t)b * 16 + tk) * 72 + f * 9;
            float s = 0.f;
            #pragma unroll
            for (int k = 0; k < 9; ++k) s += cu[k];
            S[tk * 8 + f] = s * (1.0f / 9.0f);
        }
        __syncthreads();
        float zr[64];
        #pragma unroll
        for (int k = 0; k < 16; ++k) *(float4*)&zr[k * 4] = *(const float4*)&Z[t * 72 + k * 4];
        {
            float4 a0 = make_float4(0.f, 0.f, 0.f, 0.f);
            float4 a1 = make_float4(0.f, 0.f, 0.f, 0.f);
            #pragma unroll 8
            for (int k = 0; k < 64; ++k) {
                float zk = zr[k];
                float4 w0 = *(const float4*)(weffT_s + k * 132 + (c << 2));
                float4 w1v = *(const float4*)(weffT_s + k * 132 + 64 + (c << 2));
                a0.x = fmaf(w0.x, zk, a0.x); a0.y = fmaf(w0.y, zk, a0.y);
                a0.z = fmaf(w0.z, zk, a0.z); a0.w = fmaf(w0.w, zk, a0.w);
                a1.x = fmaf(w1v.x, zk, a1.x); a1.y = fmaf(w1v.y, zk, a1.y);
                a1.z = fmaf(w1v.z, zk, a1.z); a1.w = fmaf(w1v.w, zk, a1.w);
            }
            int o0 = c << 2, o1 = 64 + (c << 2);
            float4 g0 = make_float4(gelu_f(a0.x + beff_s[o0 + 0]), gelu_f(a0.y + beff_s[o0 + 1]),
                                    gelu_f(a0.z + beff_s[o0 + 2]), gelu_f(a0.w + beff_s[o0 + 3]));
            float4 g1 = make_float4(gelu_f(a1.x + beff_s[o1 + 0]), gelu_f(a1.y + beff_s[o1 + 1]),
                                    gelu_f(a1.z + beff_s[o1 + 2]), gelu_f(a1.w + beff_s[o1 + 3]));
            *(float4*)&Bb[t * 136 + o0] = g0;
            *(float4*)&Bb[t * 136 + o1] = g1;
        }
        __syncthreads();
        float acc2 = 0.f;
        {   // conv2 16->1 + loss
            int h = c >> 3, pos = c & 7;
            float a = (h == 0) ? s_db2[0] : 0.f;
            for (int ci = h * 8; ci < h * 8 + 8; ++ci) {
                const float* w = s_dw2 + ci * 3;
                const float* hb = &Bb[t * 136 + ci * 8];
                if (pos > 0) a = fmaf(w[0], hb[pos - 1], a);
                a = fmaf(w[1], hb[pos], a);
                if (pos < 7) a = fmaf(w[2], hb[pos + 1], a);
            }
            a += __shfl_xor(a, 8);
            if (h == 0) { float df = a - S[t * 8 + pos]; acc2 = df * df; }
        }
        double s = (double)acc2;
        #pragma unroll
        for (int o = 32; o > 0; o >>= 1) s += __shfl_down(s, o);
        if ((tid & 63) == 0) wred[tid >> 6] = s;
        __syncthreads();
        if (tid == 0) p_rec_s[b] = wred[0] + wred[1] + wred[2] + wred[3];
    } else {
        // ---------------- spatial ----------------
        int b = blockIdx.x - 4608;
        float* Z = U;            // 1152
        float* H = U + 1152;     // 3200
        float* T = U + 4352;     // 1664
        {
            int tk = tid >> 4, dq = tid & 15;
            *(float4*)&Z[tk * 72 + dq * 4] =
                *(const float4*)(emb_x + (size_t)b * 1024 + (size_t)tid * 4);
        }
        for (int u = tid; u < 1152; u += 256) {
            int tk = u / 72, e = u - tk * 72;
            int ci = e / 9, p = e - ci * 9;
            T[tk * 104 + ci * 12 + p] = cubes[(size_t)b * 1152 + u];
        }
        __syncthreads();
        float zr[64];
        #pragma unroll
        for (int k = 0; k < 16; ++k) *(float4*)&zr[k * 4] = *(const float4*)&Z[t * 72 + k * 4];
        {
            float4 a0 = make_float4(0.f, 0.f, 0.f, 0.f);
            float4 a1 = make_float4(0.f, 0.f, 0.f, 0.f);
            float4 a2 = make_float4(0.f, 0.f, 0.f, 0.f);
            #pragma unroll 8
            for (int k = 0; k < 64; ++k) {
                float zk = zr[k];
                float4 w0 = *(const float4*)(weffT_x + k * 148 + (c << 2));
                float4 w1v = *(const float4*)(weffT_x + k * 148 + 64 + (c << 2));
                float4 w2v = *(const float4*)(weffT_x + k * 148 + 128 + (c << 2));
                a0.x = fmaf(w0.x, zk, a0.x); a0.y = fmaf(w0.y, zk, a0.y);
                a0.z = fmaf(w0.z, zk, a0.z); a0.w = fmaf(w0.w, zk, a0.w);
                a1.x = fmaf(w1v.x, zk, a1.x); a1.y = fmaf(w1v.y, zk, a1.y);
                a1.z = fmaf(w1v.z, zk, a1.z); a1.w = fmaf(w1v.w, zk, a1.w);
                a2.x = fmaf(w2v.x, zk, a2.x); a2.y = fmaf(w2v.y, zk, a2.y);
                a2.z = fmaf(w2v.z, zk, a2.z); a2.w = fmaf(w2v.w, zk, a2.w);
            }
            float av[12] = {a0.x, a0.y, a0.z, a0.w, a1.x, a1.y, a1.z, a1.w, a2.x, a2.y, a2.z, a2.w};
            #pragma unroll
            for (int q = 0; q < 12; ++q) {
                int o = (c << 2) + ((q >> 2) << 6) + (q & 3);
                int ch = o / 9, p = o - ch * 9;
                H[t * 200 + ch * 12 + p] = gelu_f(av[q] + beff_x[o]);
            }
        }
        __syncthreads();
        float acc2 = 0.f;
        {   // conv2 16->8 + loss
            int co = c >> 1, h = c & 1;
            float accp[9];
            #pragma unroll
            for (int p = 0; p < 9; ++p) accp[p] = (h == 0) ? x_db2[co] : 0.f;
            for (int ci = h * 8; ci < h * 8 + 8; ++ci) {
                float r[12];
                *(float4*)&r[0] = *(const float4*)&H[t * 200 + ci * 12];
                *(float4*)&r[4] = *(const float4*)&H[t * 200 + ci * 12 + 4];
                *(float4*)&r[8] = *(const float4*)&H[t * 200 + ci * 12 + 8];
                float wv[9];
                #pragma unroll
                for (int q = 0; q < 9; ++q) wv[q] = xdw2T[(ci * 9 + q) * 8 + co];
                #pragma unroll
                for (int p = 0; p < 9; ++p) {
                    int i = p / 3, j = p % 3;
                    #pragma unroll
                    for (int di = 0; di < 3; ++di) {
                        int ii = i + di - 1; if (ii < 0 || ii > 2) continue;
                        #pragma unroll
                        for (int dj = 0; dj < 3; ++dj) {
                            int jj = j + dj - 1; if (jj < 0 || jj > 2) continue;
                            accp[p] = fmaf(wv[di * 3 + dj], r[ii * 3 + jj], accp[p]);
                        }
                    }
                }
            }
            #pragma unroll
            for (int p = 0; p < 9; ++p) {
                float tot = accp[p] + __shfl_xor(accp[p], 1);
                if (h == 0) { float df = tot - T[t * 104 + co * 12 + p]; acc2 = fmaf(df, df, acc2); }
            }
        }
        double s = (double)acc2;
        #pragma unroll
        for (int o = 32; o > 0; o >>= 1) s += __shfl_down(s, o);
        if ((tid & 63) == 0) wred[tid >> 6] = s;
        __syncthreads();
        if (tid == 0) p_rec_x[b] = wred[0] + wred[1] + wred[2] + wred[3];
    }
}

// ================= finalize scalars =================
__global__ void __launch_bounds__(256) k_final(
    const double* __restrict__ p_vq_s, const double* __restrict__ p_vq_x,
    const double* __restrict__ p_rec_s, const double* __restrict__ p_rec_x,
    const int* __restrict__ hist_s, const int* __restrict__ hist_x,
    const int* __restrict__ rr,
    float* __restrict__ outscal)
{
    __shared__ double wred[4];
    int tid = threadIdx.x;
    auto bred = [&](double v) -> double {
        #pragma unroll
        for (int o = 32; o > 0; o >>= 1) v += __shfl_down(v, o);
        __syncthreads();
        if ((tid & 63) == 0) wred[tid >> 6] = v;
        __syncthreads();
        return wred[0] + wred[1] + wred[2] + wred[3];
    };
    double a;
    a = 0; for (int t = tid; t < 1152; t += 256) a += p_vq_s[t];
    double vq_s = bred(a);
    a = 0; for (int t = tid; t < 1152; t += 256) a += p_vq_x[t];
    double vq_x = bred(a);
    a = 0; for (int t = tid; t < 4608; t += 256) a += p_rec_s[t];
    double rec_s = bred(a);
    a = 0; for (int t = tid; t < 4608; t += 256) a += p_rec_x[t];
    double rec_x = bred(a);
    a = 0;
    for (int t = tid; t < 1024; t += 256) {
        double cnt = (double)hist_s[t];
        if (cnt > 0.0) { double p = cnt / (double)NTOK; a += p * log(p + 1e-10); }
    }
    double ent_s = bred(a);
    a = 0;
    for (int t = tid; t < 1024; t += 256) {
        double cnt = (double)hist_x[t];
        if (cnt > 0.0) { double p = cnt / (double)NTOK; a += p * log(p + 1e-10); }
    }
    double ent_x = bred(a);
    if (tid == 0) {
        double total = 0.25 * (vq_s / 4718592.0 + vq_x / 4718592.0);
        double rec = (rr[0] != 0) ? (rec_s / 589824.0 + rec_x / 5308416.0) : 0.0;
        outscal[0] = (float)total;
        outscal[1] = (float)exp(-ent_s);
        outscal[2] = (float)exp(-ent_x);
        outscal[3] = (float)rec;
    }
}

extern "C" void kernel_launch(void* const* d_in, const int* in_sizes, int n_in,
                              void* d_out, int out_size, void* d_ws, size_t ws_size,
                              hipStream_t stream)
{
    const float* cubes  = (const float*)d_in[0];
    const float* s_w1   = (const float*)d_in[1];
    const float* s_b1   = (const float*)d_in[2];
    const float* s_w2   = (const float*)d_in[3];
    const float* s_b2   = (const float*)d_in[4];
    const float* s_fcw  = (const float*)d_in[5];
    const float* s_fcb  = (const float*)d_in[6];
    const float* cb_s   = (const float*)d_in[7];
    const float* s_dfcw = (const float*)d_in[8];
    const float* s_dfcb = (const float*)d_in[9];
    const float* s_dw1  = (const float*)d_in[10];
    const float* s_db1  = (const float*)d_in[11];
    const float* s_dw2  = (const float*)d_in[12];
    const float* s_db2  = (const float*)d_in[13];
    const float* x_w1   = (const float*)d_in[14];
    const float* x_b1   = (const float*)d_in[15];
    const float* x_w2   = (const float*)d_in[16];
    const float* x_b2   = (const float*)d_in[17];
    const float* x_fcw  = (const float*)d_in[18];
    const float* x_fcb  = (const float*)d_in[19];
    const float* cb_x   = (const float*)d_in[20];
    const float* x_dfcw = (const float*)d_in[21];
    const float* x_dfcb = (const float*)d_in[22];
    const float* x_dw1  = (const float*)d_in[23];
    const float* x_db1  = (const float*)d_in[24];
    const float* x_dw2  = (const float*)d_in[25];
    const float* x_db2  = (const float*)d_in[26];
    const int*   rr     = (const int*)d_in[27];

    float* out   = (float*)d_out;
    float* emb_s = out;
    float* emb_x = out + 4718592;
    float* kidx  = out + 9437184;
    float* midx  = out + 9510912;
    float* scal  = out + 9584640;

    char* ws = (char*)d_ws;
    int*    hist_s  = (int*)(ws + 0);
    int*    hist_x  = (int*)(ws + 4096);
    double* cn_s    = (double*)(ws + 8192);
    double* cn_x    = (double*)(ws + 16384);
    double* p_vq_s  = (double*)(ws + 24576);   // 1152 d
    double* p_vq_x  = (double*)(ws + 33792);   // 1152 d
    double* p_rec_s = (double*)(ws + 43008);   // 4608 d
    double* p_rec_x = (double*)(ws + 79872);   // 4608 d
    float*  beff_s  = (float*)(ws + 116736);   // 128 f
    float*  beff_x  = (float*)(ws + 117248);   // 144 f
    float*  weffT_s = (float*)(ws + 117824);   // 64*132 f
    float*  weffT_x = (float*)(ws + 151616);   // 64*148 f
    float*  fcwT_s  = (float*)(ws + 189504);   // 8192 f
    float*  fcwT_x  = (float*)(ws + 222272);   // 9216 f
    float*  sw2T    = (float*)(ws + 259136);   // 768 f
    float*  xw1T    = (float*)(ws + 262208);   // 1152 f
    float*  xw2T    = (float*)(ws + 266816);   // 2304 f
    float*  xdw2T   = (float*)(ws + 276032);   // 1152 f (end 280640)

    hipMemsetAsync(d_ws, 0, 8192, stream);     // zero histograms
    k_prep<<<165, 256, 0, stream>>>(cb_s, cb_x, cn_s, cn_x,
                                    s_dw1, s_db1, s_dfcw, s_dfcb, weffT_s, beff_s,
                                    x_dw1, x_db1, x_dfcw, x_dfcb, weffT_x, beff_x,
                                    s_fcw, fcwT_s, x_fcw, fcwT_x,
                                    s_w2, sw2T, x_w1, xw1T, x_w2, xw2T, x_dw2, xdw2T);
    k_enc<<<9216, 256, 0, stream>>>(cubes, s_w1, s_b1, sw2T, s_b2, fcwT_s, s_fcb, emb_s,
                                    xw1T, x_b1, xw2T, x_b2, fcwT_x, x_fcb, emb_x);
    k_vq<<<2304, 256, 0, stream>>>(emb_s, emb_x, cb_s, cb_x, cn_s, cn_x,
                                   kidx, midx, hist_s, hist_x, p_vq_s, p_vq_x);
    k_dec<<<9216, 256, 0, stream>>>(emb_s, emb_x, cubes,
                                    weffT_s, beff_s, s_dw2, s_db2,
                                    weffT_x, beff_x, xdw2T, x_db2,
                                    p_rec_s, p_rec_x);
    k_final<<<1, 256, 0, stream>>>(p_vq_s, p_vq_x, p_rec_s, p_rec_x, hist_s, hist_x, rr, scal);
}

// Round 9
// 882.739 us; speedup vs baseline: 2.8335x; 1.1644x over previous
//
#include <hip/hip_runtime.h>
#include <math.h>

#define NTOK 73728

__device__ __forceinline__ float gelu_f(float x) {
    return 0.5f * x * (1.0f + erff(x * 0.70710678118654752440f));
}

// ================= prep: norms, fused dec weights, transposes =================
__global__ void __launch_bounds__(256) k_prep(
    const float* __restrict__ cb_s, const float* __restrict__ cb_x,
    double* __restrict__ cn_s, double* __restrict__ cn_x,
    const float* __restrict__ s_dw1, const float* __restrict__ s_db1,
    const float* __restrict__ s_dfcw, const float* __restrict__ s_dfcb,
    float* __restrict__ weffT_s, float* __restrict__ beff_s,
    const float* __restrict__ x_dw1, const float* __restrict__ x_db1,
    const float* __restrict__ x_dfcw, const float* __restrict__ x_dfcb,
    float* __restrict__ weffT_x, float* __restrict__ beff_x,
    const float* __restrict__ s_fcw, float* __restrict__ fcwT_s,
    const float* __restrict__ x_fcw, float* __restrict__ fcwT_x,
    const float* __restrict__ s_w2, float* __restrict__ sw2T,
    const float* __restrict__ x_w1, float* __restrict__ xw1T,
    const float* __restrict__ x_w2, float* __restrict__ xw2T,
    const float* __restrict__ x_dw2, float* __restrict__ xdw2T)
{
    int bid = blockIdx.x, tid = threadIdx.x;
    if (bid < 8) {                     // codebook norms (f64)
        int i = bid * 256 + tid;
        const float* cb = (i < 1024) ? cb_s : cb_x;
        double* cn = (i < 1024) ? cn_s : cn_x;
        int c = i & 1023;
        double s = 0.0;
        for (int k = 0; k < 64; ++k) { double v = (double)cb[c * 64 + k]; s += v * v; }
        cn[c] = s;
    } else if (bid < 40) {             // weffT_s
        int idx = (bid - 8) * 256 + tid;
        int o = idx >> 6, d = idx & 63;
        int c = o >> 3, l = o & 7;
        double acc = 0.0;
        for (int ci = 0; ci < 16; ++ci)
            for (int dd = 0; dd < 3; ++dd) {
                int ll = l + dd - 1;
                if (ll < 0 || ll > 7) continue;
                acc += (double)s_dw1[(c * 16 + ci) * 3 + dd] * (double)s_dfcw[(ci * 8 + ll) * 64 + d];
            }
        weffT_s[d * 132 + o] = (float)acc;
        if (o < 4) weffT_s[d * 132 + 128 + o] = 0.f;
        if (d == 0) {
            double bb = (double)s_db1[c];
            for (int ci = 0; ci < 16; ++ci)
                for (int dd = 0; dd < 3; ++dd) {
                    int ll = l + dd - 1;
                    if (ll < 0 || ll > 7) continue;
                    bb += (double)s_dw1[(c * 16 + ci) * 3 + dd] * (double)s_dfcb[ci * 8 + ll];
                }
            beff_s[o] = (float)bb;
        }
    } else if (bid < 76) {             // weffT_x
        int idx = (bid - 40) * 256 + tid;
        int o = idx >> 6, d = idx & 63;
        int c = o / 9, p = o - c * 9;
        int i = p / 3, j = p % 3;
        double acc = 0.0;
        for (int ci = 0; ci < 16; ++ci)
            for (int di = 0; di < 3; ++di) {
                int ii = i + di - 1; if (ii < 0 || ii > 2) continue;
                for (int dj = 0; dj < 3; ++dj) {
                    int jj = j + dj - 1; if (jj < 0 || jj > 2) continue;
                    acc += (double)x_dw1[((c * 16 + ci) * 3 + di) * 3 + dj]
                         * (double)x_dfcw[(ci * 9 + ii * 3 + jj) * 64 + d];
                }
            }
        weffT_x[d * 148 + o] = (float)acc;
        if (o < 4) weffT_x[d * 148 + 144 + o] = 0.f;
        if (d == 0) {
            double bb = (double)x_db1[c];
            for (int ci = 0; ci < 16; ++ci)
                for (int di = 0; di < 3; ++di) {
                    int ii = i + di - 1; if (ii < 0 || ii > 2) continue;
                    for (int dj = 0; dj < 3; ++dj) {
                        int jj = j + dj - 1; if (jj < 0 || jj > 2) continue;
                        bb += (double)x_dw1[((c * 16 + ci) * 3 + di) * 3 + dj]
                            * (double)x_dfcb[ci * 9 + ii * 3 + jj];
                    }
                }
            beff_x[o] = (float)bb;
        }
    } else if (bid < 108) {            // fcwT_s
        int i = (bid - 76) * 256 + tid;
        fcwT_s[i] = s_fcw[(i & 63) * 128 + (i >> 6)];
    } else if (bid < 144) {            // fcwT_x
        int i = (bid - 108) * 256 + tid;
        fcwT_x[i] = x_fcw[(i & 63) * 144 + (i >> 6)];
    } else {                           // small conv-weight transposes
        int i = (bid - 144) * 256 + tid;
        if (i < 768) {
            int c = i & 15, r = i >> 4;
            int ci = r / 3, dd = r % 3;
            sw2T[i] = s_w2[(c * 16 + ci) * 3 + dd];
        } else if (i < 1920) {
            int j = i - 768;
            int c = j & 15, r = j >> 4;
            int ci = r / 9, tap = r % 9;
            xw1T[j] = x_w1[(c * 8 + ci) * 9 + tap];
        } else if (i < 4224) {
            int j = i - 1920;
            int c = j & 15, r = j >> 4;
            int ci = r / 9, tap = r % 9;
            xw2T[j] = x_w2[(c * 16 + ci) * 9 + tap];
        } else {
            int j = i - 4224;
            int co = j & 7, r = j >> 3;
            int ci = r / 9, tap = r % 9;
            xdw2T[j] = x_dw2[(co * 16 + ci) * 9 + tap];
        }
    }
}

// ================= merged encoders: blocks [0,4608) spectral, [4608,9216) spatial =================
__global__ void __launch_bounds__(256) k_enc(
    const float* __restrict__ cubes,
    const float* __restrict__ s_w1, const float* __restrict__ s_b1,
    const float* __restrict__ sw2T, const float* __restrict__ s_b2,
    const float* __restrict__ fcwT_s, const float* __restrict__ s_fcb,
    float* __restrict__ emb_s,
    const float* __restrict__ xw1T, const float* __restrict__ x_b1,
    const float* __restrict__ xw2T, const float* __restrict__ x_b2,
    const float* __restrict__ fcwT_x, const float* __restrict__ x_fcb,
    float* __restrict__ emb_x)
{
    __shared__ float U[6528];
    int tid = threadIdx.x;
    int t = tid >> 4, c = tid & 15;
    if (blockIdx.x < 4608) {
        // ---------------- spectral ----------------
        int b = blockIdx.x;
        float* S = U;            // 128
        float* A = U + 128;      // 2176
        float* Bb = U + 2304;    // 2176
        if (tid < 128) {
            int tk = tid >> 3, f = tid & 7;
            const float* cu = cubes + ((size_t)b * 16 + tk) * 72 + f * 9;
            float s = 0.f;
            #pragma unroll
            for (int k = 0; k < 9; ++k) s += cu[k];
            S[tk * 8 + f] = s * (1.0f / 9.0f);
        }
        __syncthreads();
        {   // conv1 1->16
            float s0[8];
            *(float4*)&s0[0] = *(const float4*)&S[t * 8];
            *(float4*)&s0[4] = *(const float4*)&S[t * 8 + 4];
            float wa = s_w1[c * 3 + 0], wb = s_w1[c * 3 + 1], wc = s_w1[c * 3 + 2], bb = s_b1[c];
            #pragma unroll
            for (int l = 0; l < 8; ++l) {
                float v = fmaf(wb, s0[l], bb);
                if (l > 0) v = fmaf(wa, s0[l - 1], v);
                if (l < 7) v = fmaf(wc, s0[l + 1], v);
                A[t * 136 + c * 8 + l] = gelu_f(v);
            }
        }
        __syncthreads();
        {   // conv2 16->16
            float acc[8];
            #pragma unroll
            for (int l = 0; l < 8; ++l) acc[l] = s_b2[c];
            for (int ci = 0; ci < 16; ++ci) {
                float r[8];
                *(float4*)&r[0] = *(const float4*)&A[t * 136 + ci * 8];
                *(float4*)&r[4] = *(const float4*)&A[t * 136 + ci * 8 + 4];
                float wa = sw2T[(ci * 3 + 0) * 16 + c];
                float wb = sw2T[(ci * 3 + 1) * 16 + c];
                float wc = sw2T[(ci * 3 + 2) * 16 + c];
                #pragma unroll
                for (int l = 0; l < 8; ++l) {
                    if (l > 0) acc[l] = fmaf(wa, r[l - 1], acc[l]);
                    acc[l] = fmaf(wb, r[l], acc[l]);
                    if (l < 7) acc[l] = fmaf(wc, r[l + 1], acc[l]);
                }
            }
            #pragma unroll
            for (int l = 0; l < 8; ++l) Bb[t * 136 + c * 8 + l] = gelu_f(acc[l]);
        }
        __syncthreads();
        {   // fc 128->64
            float4 zv = make_float4(s_fcb[c * 4 + 0], s_fcb[c * 4 + 1], s_fcb[c * 4 + 2], s_fcb[c * 4 + 3]);
            #pragma unroll 4
            for (int e = 0; e < 128; ++e) {
                float be = Bb[t * 136 + e];
                float4 wv = *(const float4*)(fcwT_s + (e << 6) + (c << 2));
                zv.x = fmaf(wv.x, be, zv.x);
                zv.y = fmaf(wv.y, be, zv.y);
                zv.z = fmaf(wv.z, be, zv.z);
                zv.w = fmaf(wv.w, be, zv.w);
            }
            *(float4*)(emb_s + ((size_t)b * 16 + t) * 64 + c * 4) = zv;
        }
    } else {
        // ---------------- spatial ----------------
        int b = blockIdx.x - 4608;
        float* A = U;            // 3200
        float* Bb = U + 3200;    // 3200
        for (int u = tid; u < 1152; u += 256) {
            int tk = u / 72, e = u - tk * 72;
            int ci = e / 9, p = e - ci * 9;
            A[tk * 200 + ci * 12 + p] = cubes[(size_t)b * 1152 + u];
        }
        __syncthreads();
        {   // conv1 8->16
            float acc[9];
            #pragma unroll
            for (int p = 0; p < 9; ++p) acc[p] = x_b1[c];
            for (int ci = 0; ci < 8; ++ci) {
                float r[12];
                *(float4*)&r[0] = *(const float4*)&A[t * 200 + ci * 12];
                *(float4*)&r[4] = *(const float4*)&A[t * 200 + ci * 12 + 4];
                *(float4*)&r[8] = *(const float4*)&A[t * 200 + ci * 12 + 8];
                float wv[9];
                #pragma unroll
                for (int q = 0; q < 9; ++q) wv[q] = xw1T[(ci * 9 + q) * 16 + c];
                #pragma unroll
                for (int p = 0; p < 9; ++p) {
                    int i = p / 3, j = p % 3;
                    #pragma unroll
                    for (int di = 0; di < 3; ++di) {
                        int ii = i + di - 1; if (ii < 0 || ii > 2) continue;
                        #pragma unroll
                        for (int dj = 0; dj < 3; ++dj) {
                            int jj = j + dj - 1; if (jj < 0 || jj > 2) continue;
                            acc[p] = fmaf(wv[di * 3 + dj], r[ii * 3 + jj], acc[p]);
                        }
                    }
                }
            }
            #pragma unroll
            for (int p = 0; p < 9; ++p) Bb[t * 200 + c * 12 + p] = gelu_f(acc[p]);
        }
        __syncthreads();
        {   // conv2 16->16
            float acc[9];
            #pragma unroll
            for (int p = 0; p < 9; ++p) acc[p] = x_b2[c];
            for (int ci = 0; ci < 16; ++ci) {
                float r[12];
                *(float4*)&r[0] = *(const float4*)&Bb[t * 200 + ci * 12];
                *(float4*)&r[4] = *(const float4*)&Bb[t * 200 + ci * 12 + 4];
                *(float4*)&r[8] = *(const float4*)&Bb[t * 200 + ci * 12 + 8];
                float wv[9];
                #pragma unroll
                for (int q = 0; q < 9; ++q) wv[q] = xw2T[(ci * 9 + q) * 16 + c];
                #pragma unroll
                for (int p = 0; p < 9; ++p) {
                    int i = p / 3, j = p % 3;
                    #pragma unroll
                    for (int di = 0; di < 3; ++di) {
                        int ii = i + di - 1; if (ii < 0 || ii > 2) continue;
                        #pragma unroll
                        for (int dj = 0; dj < 3; ++dj) {
                            int jj = j + dj - 1; if (jj < 0 || jj > 2) continue;
                            acc[p] = fmaf(wv[di * 3 + dj], r[ii * 3 + jj], acc[p]);
                        }
                    }
                }
            }
            __syncthreads();
            #pragma unroll
            for (int p = 0; p < 9; ++p) A[t * 200 + c * 12 + p] = gelu_f(acc[p]);
        }
        __syncthreads();
        {   // fc 144->64
            float4 zv = make_float4(x_fcb[c * 4 + 0], x_fcb[c * 4 + 1], x_fcb[c * 4 + 2], x_fcb[c * 4 + 3]);
            #pragma unroll 4
            for (int e = 0; e < 144; ++e) {
                int ci = e / 9, p = e - ci * 9;
                float be = A[t * 200 + ci * 12 + p];
                float4 wv = *(const float4*)(fcwT_x + (e << 6) + (c << 2));
                zv.x = fmaf(wv.x, be, zv.x);
                zv.y = fmaf(wv.y, be, zv.y);
                zv.z = fmaf(wv.z, be, zv.z);
                zv.w = fmaf(wv.w, be, zv.w);
            }
            *(float4*)(emb_x + ((size_t)b * 16 + t) * 64 + c * 4) = zv;
        }
    }
}

// ===== merged VQ (R3 structure): blocks [0,1152) spectral, [1152,2304) spatial =====
__global__ void __launch_bounds__(256) k_vq(
    float* __restrict__ emb_s, float* __restrict__ emb_x,
    const float* __restrict__ cb_s, const float* __restrict__ cb_x,
    const double* __restrict__ cn_s, const double* __restrict__ cn_x,
    float* __restrict__ kidx, float* __restrict__ midx,
    int* __restrict__ hist_s, int* __restrict__ hist_x,
    double* __restrict__ p_vq_s, double* __restrict__ p_vq_x)
{
    __shared__ double pbest[4][64];
    __shared__ int pidx[4][64];
    __shared__ int lh[1024];
    int blk = blockIdx.x;
    int path = (blk >= 1152) ? 1 : 0;
    int b = blk - (path << 10) - (path << 7);          // blk - path*1152
    float* emb = path ? emb_x : emb_s;
    const float* cb = path ? cb_x : cb_s;
    const double* cn = path ? cn_x : cn_s;
    float* idx_out = path ? midx : kidx;
    int* hist = path ? hist_x : hist_s;
    double* partial = path ? p_vq_x : p_vq_s;

    int tid = threadIdx.x;
    int w = tid >> 6, l = tid & 63;
    for (int u = tid; u < 1024; u += 256) lh[u] = 0;
    size_t n = (size_t)b * 64 + l;
    float z[64];
    {
        const float4* zp = (const float4*)(emb + n * 64);
        #pragma unroll
        for (int k = 0; k < 16; ++k) *(float4*)&z[k * 4] = zp[k];
    }
    // force wave-uniform base -> SGPR codebook pointer -> s_load + v_fmac(sgpr)
    int base = __builtin_amdgcn_readfirstlane(w << 8);
    const float* crb = cb + ((size_t)base << 6);
    const double* cnb = cn + base;
    double best = 1e300; int bi = base;
    for (int cc = 0; cc < 256; ++cc) {
        const float* cr = crb + (cc << 6);
        float d0 = 0.f, d1 = 0.f, d2 = 0.f, d3 = 0.f;
        #pragma unroll
        for (int k = 0; k < 64; k += 4) {
            d0 = fmaf(z[k + 0], cr[k + 0], d0);
            d1 = fmaf(z[k + 1], cr[k + 1], d1);
            d2 = fmaf(z[k + 2], cr[k + 2], d2);
            d3 = fmaf(z[k + 3], cr[k + 3], d3);
        }
        float dot = (d0 + d1) + (d2 + d3);
        double dd = cnb[cc] - 2.0 * (double)dot;
        if (dd < best) { best = dd; bi = base + cc; }   // strict <: first-index
    }
    pbest[w][l] = best; pidx[w][l] = bi;
    __syncthreads();
    if (w == 0) {
        double bB = pbest[0][l]; int bj = pidx[0][l];
        #pragma unroll
        for (int q = 1; q < 4; ++q) {                   // ascending chunks, strict <
            double d = pbest[q][l];
            if (d < bB) { bB = d; bj = pidx[q][l]; }
        }
        idx_out[n] = (float)bj;
        float qv[64];
        {
            const float4* cq = (const float4*)(cb + ((size_t)bj << 6));
            #pragma unroll
            for (int k = 0; k < 16; ++k) *(float4*)&qv[k * 4] = cq[k];
        }
        float vs = 0.f;
        #pragma unroll
        for (int k = 0; k < 64; ++k) { float df = z[k] - qv[k]; vs = fmaf(df, df, vs); }
        float4* zo = (float4*)(emb + n * 64);
        #pragma unroll
        for (int k = 0; k < 16; ++k) zo[k] = *(float4*)&qv[k * 4];
        atomicAdd(&lh[bj], 1);
        double s = (double)vs;
        #pragma unroll
        for (int o = 32; o > 0; o >>= 1) s += __shfl_down(s, o);
        if (l == 0) partial[b] = s;
    }
    __syncthreads();
    for (int u = tid; u < 1024; u += 256) if (lh[u] > 0) atomicAdd(&hist[u], lh[u]);
}

// ================= merged decoders: blocks [0,4608) spectral, [4608,9216) spatial =================
// z read directly from LDS in the matvec (no zr[64] register array -> no scratch spill)
__global__ void __launch_bounds__(256) k_dec(
    const float* __restrict__ emb_s, const float* __restrict__ emb_x,
    const float* __restrict__ cubes,
    const float* __restrict__ weffT_s, const float* __restrict__ beff_s,
    const float* __restrict__ s_dw2, const float* __restrict__ s_db2,
    const float* __restrict__ weffT_x, const float* __restrict__ beff_x,
    const float* __restrict__ xdw2T, const float* __restrict__ x_db2,
    double* __restrict__ p_rec_s, double* __restrict__ p_rec_x)
{
    __shared__ float U[6016];
    __shared__ double wred[4];
    int tid = threadIdx.x;
    int t = tid >> 4, c = tid & 15;
    if (blockIdx.x < 4608) {
        // ---------------- spectral ----------------
        int b = blockIdx.x;
        float* Z = U;            // 1152 (stride 72)
        float* Bb = U + 1152;    // 2176
        float* S = U + 3328;     // 128
        {
            int tk = tid >> 4, dq = tid & 15;
            *(float4*)&Z[tk * 72 + dq * 4] =
                *(const float4*)(emb_s + (size_t)b * 1024 + (size_t)tid * 4);
        }
        if (tid < 128) {
            int tk = tid >> 3, f = tid & 7;
            const float* cu = cubes + ((size_t)b * 16 + tk) * 72 + f * 9;
            float s = 0.f;
            #pragma unroll
            for (int k = 0; k < 9; ++k) s += cu[k];
            S[tk * 8 + f] = s * (1.0f / 9.0f);
        }
        __syncthreads();
        {
            float4 a0 = make_float4(0.f, 0.f, 0.f, 0.f);
            float4 a1 = make_float4(0.f, 0.f, 0.f, 0.f);
            #pragma unroll 8
            for (int k = 0; k < 64; ++k) {
                float zk = Z[t * 72 + k];          // LDS broadcast read, no reg array
                float4 w0 = *(const float4*)(weffT_s + k * 132 + (c << 2));
                float4 w1v = *(const float4*)(weffT_s + k * 132 + 64 + (c << 2));
                a0.x = fmaf(w0.x, zk, a0.x); a0.y = fmaf(w0.y, zk, a0.y);
                a0.z = fmaf(w0.z, zk, a0.z); a0.w = fmaf(w0.w, zk, a0.w);
                a1.x = fmaf(w1v.x, zk, a1.x); a1.y = fmaf(w1v.y, zk, a1.y);
                a1.z = fmaf(w1v.z, zk, a1.z); a1.w = fmaf(w1v.w, zk, a1.w);
            }
            int o0 = c << 2, o1 = 64 + (c << 2);
            float4 g0 = make_float4(gelu_f(a0.x + beff_s[o0 + 0]), gelu_f(a0.y + beff_s[o0 + 1]),
                                    gelu_f(a0.z + beff_s[o0 + 2]), gelu_f(a0.w + beff_s[o0 + 3]));
            float4 g1 = make_float4(gelu_f(a1.x + beff_s[o1 + 0]), gelu_f(a1.y + beff_s[o1 + 1]),
                                    gelu_f(a1.z + beff_s[o1 + 2]), gelu_f(a1.w + beff_s[o1 + 3]));
            *(float4*)&Bb[t * 136 + o0] = g0;
            *(float4*)&Bb[t * 136 + o1] = g1;
        }
        __syncthreads();
        float acc2 = 0.f;
        {   // conv2 16->1 + loss
            int h = c >> 3, pos = c & 7;
            float a = (h == 0) ? s_db2[0] : 0.f;
            for (int ci = h * 8; ci < h * 8 + 8; ++ci) {
                const float* w = s_dw2 + ci * 3;
                const float* hb = &Bb[t * 136 + ci * 8];
                if (pos > 0) a = fmaf(w[0], hb[pos - 1], a);
                a = fmaf(w[1], hb[pos], a);
                if (pos < 7) a = fmaf(w[2], hb[pos + 1], a);
            }
            a += __shfl_xor(a, 8);
            if (h == 0) { float df = a - S[t * 8 + pos]; acc2 = df * df; }
        }
        double s = (double)acc2;
        #pragma unroll
        for (int o = 32; o > 0; o >>= 1) s += __shfl_down(s, o);
        if ((tid & 63) == 0) wred[tid >> 6] = s;
        __syncthreads();
        if (tid == 0) p_rec_s[b] = wred[0] + wred[1] + wred[2] + wred[3];
    } else {
        // ---------------- spatial ----------------
        int b = blockIdx.x - 4608;
        float* Z = U;            // 1152
        float* H = U + 1152;     // 3200
        float* T = U + 4352;     // 1664
        {
            int tk = tid >> 4, dq = tid & 15;
            *(float4*)&Z[tk * 72 + dq * 4] =
                *(const float4*)(emb_x + (size_t)b * 1024 + (size_t)tid * 4);
        }
        for (int u = tid; u < 1152; u += 256) {
            int tk = u / 72, e = u - tk * 72;
            int ci = e / 9, p = e - ci * 9;
            T[tk * 104 + ci * 12 + p] = cubes[(size_t)b * 1152 + u];
        }
        __syncthreads();
        {
            float4 a0 = make_float4(0.f, 0.f, 0.f, 0.f);
            float4 a1 = make_float4(0.f, 0.f, 0.f, 0.f);
            float4 a2 = make_float4(0.f, 0.f, 0.f, 0.f);
            #pragma unroll 8
            for (int k = 0; k < 64; ++k) {
                float zk = Z[t * 72 + k];          // LDS broadcast read, no reg array
                float4 w0 = *(const float4*)(weffT_x + k * 148 + (c << 2));
                float4 w1v = *(const float4*)(weffT_x + k * 148 + 64 + (c << 2));
                float4 w2v = *(const float4*)(weffT_x + k * 148 + 128 + (c << 2));
                a0.x = fmaf(w0.x, zk, a0.x); a0.y = fmaf(w0.y, zk, a0.y);
                a0.z = fmaf(w0.z, zk, a0.z); a0.w = fmaf(w0.w, zk, a0.w);
                a1.x = fmaf(w1v.x, zk, a1.x); a1.y = fmaf(w1v.y, zk, a1.y);
                a1.z = fmaf(w1v.z, zk, a1.z); a1.w = fmaf(w1v.w, zk, a1.w);
                a2.x = fmaf(w2v.x, zk, a2.x); a2.y = fmaf(w2v.y, zk, a2.y);
                a2.z = fmaf(w2v.z, zk, a2.z); a2.w = fmaf(w2v.w, zk, a2.w);
            }
            float av[12] = {a0.x, a0.y, a0.z, a0.w, a1.x, a1.y, a1.z, a1.w, a2.x, a2.y, a2.z, a2.w};
            #pragma unroll
            for (int q = 0; q < 12; ++q) {
                int o = (c << 2) + ((q >> 2) << 6) + (q & 3);
                int ch = o / 9, p = o - ch * 9;
                H[t * 200 + ch * 12 + p] = gelu_f(av[q] + beff_x[o]);
            }
        }
        __syncthreads();
        float acc2 = 0.f;
        {   // conv2 16->8 + loss
            int co = c >> 1, h = c & 1;
            float accp[9];
            #pragma unroll
            for (int p = 0; p < 9; ++p) accp[p] = (h == 0) ? x_db2[co] : 0.f;
            for (int ci = h * 8; ci < h * 8 + 8; ++ci) {
                float r[12];
                *(float4*)&r[0] = *(const float4*)&H[t * 200 + ci * 12];
                *(float4*)&r[4] = *(const float4*)&H[t * 200 + ci * 12 + 4];
                *(float4*)&r[8] = *(const float4*)&H[t * 200 + ci * 12 + 8];
                float wv[9];
                #pragma unroll
                for (int q = 0; q < 9; ++q) wv[q] = xdw2T[(ci * 9 + q) * 8 + co];
                #pragma unroll
                for (int p = 0; p < 9; ++p) {
                    int i = p / 3, j = p % 3;
                    #pragma unroll
                    for (int di = 0; di < 3; ++di) {
                        int ii = i + di - 1; if (ii < 0 || ii > 2) continue;
                        #pragma unroll
                        for (int dj = 0; dj < 3; ++dj) {
                            int jj = j + dj - 1; if (jj < 0 || jj > 2) continue;
                            accp[p] = fmaf(wv[di * 3 + dj], r[ii * 3 + jj], accp[p]);
                        }
                    }
                }
            }
            #pragma unroll
            for (int p = 0; p < 9; ++p) {
                float tot = accp[p] + __shfl_xor(accp[p], 1);
                if (h == 0) { float df = tot - T[t * 104 + co * 12 + p]; acc2 = fmaf(df, df, acc2); }
            }
        }
        double s = (double)acc2;
        #pragma unroll
        for (int o = 32; o > 0; o >>= 1) s += __shfl_down(s, o);
        if ((tid & 63) == 0) wred[tid >> 6] = s;
        __syncthreads();
        if (tid == 0) p_rec_x[b] = wred[0] + wred[1] + wred[2] + wred[3];
    }
}

// ================= finalize scalars =================
__global__ void __launch_bounds__(256) k_final(
    const double* __restrict__ p_vq_s, const double* __restrict__ p_vq_x,
    const double* __restrict__ p_rec_s, const double* __restrict__ p_rec_x,
    const int* __restrict__ hist_s, const int* __restrict__ hist_x,
    const int* __restrict__ rr,
    float* __restrict__ outscal)
{
    __shared__ double wred[4];
    int tid = threadIdx.x;
    auto bred = [&](double v) -> double {
        #pragma unroll
        for (int o = 32; o > 0; o >>= 1) v += __shfl_down(v, o);
        __syncthreads();
        if ((tid & 63) == 0) wred[tid >> 6] = v;
        __syncthreads();
        return wred[0] + wred[1] + wred[2] + wred[3];
    };
    double a;
    a = 0; for (int t = tid; t < 1152; t += 256) a += p_vq_s[t];
    double vq_s = bred(a);
    a = 0; for (int t = tid; t < 1152; t += 256) a += p_vq_x[t];
    double vq_x = bred(a);
    a = 0; for (int t = tid; t < 4608; t += 256) a += p_rec_s[t];
    double rec_s = bred(a);
    a = 0; for (int t = tid; t < 4608; t += 256) a += p_rec_x[t];
    double rec_x = bred(a);
    a = 0;
    for (int t = tid; t < 1024; t += 256) {
        double cnt = (double)hist_s[t];
        if (cnt > 0.0) { double p = cnt / (double)NTOK; a += p * log(p + 1e-10); }
    }
    double ent_s = bred(a);
    a = 0;
    for (int t = tid; t < 1024; t += 256) {
        double cnt = (double)hist_x[t];
        if (cnt > 0.0) { double p = cnt / (double)NTOK; a += p * log(p + 1e-10); }
    }
    double ent_x = bred(a);
    if (tid == 0) {
        double total = 0.25 * (vq_s / 4718592.0 + vq_x / 4718592.0);
        double rec = (rr[0] != 0) ? (rec_s / 589824.0 + rec_x / 5308416.0) : 0.0;
        outscal[0] = (float)total;
        outscal[1] = (float)exp(-ent_s);
        outscal[2] = (float)exp(-ent_x);
        outscal[3] = (float)rec;
    }
}

extern "C" void kernel_launch(void* const* d_in, const int* in_sizes, int n_in,
                              void* d_out, int out_size, void* d_ws, size_t ws_size,
                              hipStream_t stream)
{
    const float* cubes  = (const float*)d_in[0];
    const float* s_w1   = (const float*)d_in[1];
    const float* s_b1   = (const float*)d_in[2];
    const float* s_w2   = (const float*)d_in[3];
    const float* s_b2   = (const float*)d_in[4];
    const float* s_fcw  = (const float*)d_in[5];
    const float* s_fcb  = (const float*)d_in[6];
    const float* cb_s   = (const float*)d_in[7];
    const float* s_dfcw = (const float*)d_in[8];
    const float* s_dfcb = (const float*)d_in[9];
    const float* s_dw1  = (const float*)d_in[10];
    const float* s_db1  = (const float*)d_in[11];
    const float* s_dw2  = (const float*)d_in[12];
    const float* s_db2  = (const float*)d_in[13];
    const float* x_w1   = (const float*)d_in[14];
    const float* x_b1   = (const float*)d_in[15];
    const float* x_w2   = (const float*)d_in[16];
    const float* x_b2   = (const float*)d_in[17];
    const float* x_fcw  = (const float*)d_in[18];
    const float* x_fcb  = (const float*)d_in[19];
    const float* cb_x   = (const float*)d_in[20];
    const float* x_dfcw = (const float*)d_in[21];
    const float* x_dfcb = (const float*)d_in[22];
    const float* x_dw1  = (const float*)d_in[23];
    const float* x_db1  = (const float*)d_in[24];
    const float* x_dw2  = (const float*)d_in[25];
    const float* x_db2  = (const float*)d_in[26];
    const int*   rr     = (const int*)d_in[27];

    float* out   = (float*)d_out;
    float* emb_s = out;
    float* emb_x = out + 4718592;
    float* kidx  = out + 9437184;
    float* midx  = out + 9510912;
    float* scal  = out + 9584640;

    char* ws = (char*)d_ws;
    int*    hist_s  = (int*)(ws + 0);
    int*    hist_x  = (int*)(ws + 4096);
    double* cn_s    = (double*)(ws + 8192);
    double* cn_x    = (double*)(ws + 16384);
    double* p_vq_s  = (double*)(ws + 24576);   // 1152 d
    double* p_vq_x  = (double*)(ws + 33792);   // 1152 d
    double* p_rec_s = (double*)(ws + 43008);   // 4608 d
    double* p_rec_x = (double*)(ws + 79872);   // 4608 d
    float*  beff_s  = (float*)(ws + 116736);   // 128 f
    float*  beff_x  = (float*)(ws + 117248);   // 144 f
    float*  weffT_s = (float*)(ws + 117824);   // 64*132 f
    float*  weffT_x = (float*)(ws + 151616);   // 64*148 f
    float*  fcwT_s  = (float*)(ws + 189504);   // 8192 f
    float*  fcwT_x  = (float*)(ws + 222272);   // 9216 f
    float*  sw2T    = (float*)(ws + 259136);   // 768 f
    float*  xw1T    = (float*)(ws + 262208);   // 1152 f
    float*  xw2T    = (float*)(ws + 266816);   // 2304 f
    float*  xdw2T   = (float*)(ws + 276032);   // 1152 f (end 280640)

    hipMemsetAsync(d_ws, 0, 8192, stream);     // zero histograms
    k_prep<<<165, 256, 0, stream>>>(cb_s, cb_x, cn_s, cn_x,
                                    s_dw1, s_db1, s_dfcw, s_dfcb, weffT_s, beff_s,
                                    x_dw1, x_db1, x_dfcw, x_dfcb, weffT_x, beff_x,
                                    s_fcw, fcwT_s, x_fcw, fcwT_x,
                                    s_w2, sw2T, x_w1, xw1T, x_w2, xw2T, x_dw2, xdw2T);
    k_enc<<<9216, 256, 0, stream>>>(cubes, s_w1, s_b1, sw2T, s_b2, fcwT_s, s_fcb, emb_s,
                                    xw1T, x_b1, xw2T, x_b2, fcwT_x, x_fcb, emb_x);
    k_vq<<<2304, 256, 0, stream>>>(emb_s, emb_x, cb_s, cb_x, cn_s, cn_x,
                                   kidx, midx, hist_s, hist_x, p_vq_s, p_vq_x);
    k_dec<<<9216, 256, 0, stream>>>(emb_s, emb_x, cubes,
                                    weffT_s, beff_s, s_dw2, s_db2,
                                    weffT_x, beff_x, xdw2T, x_db2,
                                    p_rec_s, p_rec_x);
    k_final<<<1, 256, 0, stream>>>(p_vq_s, p_vq_x, p_rec_s, p_rec_x, hist_s, hist_x, rr, scal);
}